// Round 13
// baseline (2796.570 us; speedup 1.0000x reference)
//
#include <hip/hip_runtime.h>

typedef __bf16 bf16;
typedef __attribute__((ext_vector_type(8))) __bf16 bf16x8;
typedef __attribute__((ext_vector_type(4))) __bf16 bf16x4;
typedef __attribute__((ext_vector_type(4))) float f32x4;

#define NL 6
#define DIM 1024
#define NH 16
#define DH 64
#define TT 2048
#define BB 2
#define BT 4096
#define FFD 4096
#define NSLOT 4096
#define NV 32000

__device__ __forceinline__ void gld16(const void* g, void* l) {
  __builtin_amdgcn_global_load_lds(
      (const __attribute__((address_space(1))) void*)g,
      (__attribute__((address_space(3))) void*)l, 16, 0, 0);
}

// ---------------- conversion / transpose kernels ----------------

__global__ void cvt_bf16(const float* __restrict__ s, bf16* __restrict__ d, long n) {
  long i = ((long)blockIdx.x * 256 + threadIdx.x) * 4;
  if (i + 3 < n) {
    float4 v = *(const float4*)(s + i);
    bf16x4 o = {(bf16)v.x, (bf16)v.y, (bf16)v.z, (bf16)v.w};
    *(bf16x4*)(d + i) = o;
  }
}

// Batched transpose: up to 7 segments in one launch (verified R12 body).
struct TBatch {
  const float* src[7];
  bf16* dst[7];
  int R[7], C[7];
  int base[7];
};

__device__ __forceinline__ void transpose_tile_body(
    const float* __restrict__ src, bf16* __restrict__ dst, int R, int C, int local) {
  const int tilesPerRow = C / 32;
  const int c0 = (local % tilesPerRow) * 32;
  const int r0 = (local / tilesPerRow) * 32;
  __shared__ float tile[32][33];
  int tx = threadIdx.x;  // 0..7
  int ty = threadIdx.y;  // 0..31
  float4 v = *(const float4*)(src + (size_t)(r0 + ty) * C + c0 + tx * 4);
  tile[ty][tx * 4 + 0] = v.x;
  tile[ty][tx * 4 + 1] = v.y;
  tile[ty][tx * 4 + 2] = v.z;
  tile[ty][tx * 4 + 3] = v.w;
  __syncthreads();
  bf16x4 o = {(bf16)tile[tx * 4 + 0][ty], (bf16)tile[tx * 4 + 1][ty],
              (bf16)tile[tx * 4 + 2][ty], (bf16)tile[tx * 4 + 3][ty]};
  *(bf16x4*)(dst + (size_t)(c0 + ty) * R + r0 + tx * 4) = o;
}

__global__ void transpose_cvt_batch(TBatch tb) {
  const int bid = blockIdx.x;
  int s = 0;
#pragma unroll
  for (int i = 1; i < 7; ++i)
    if (bid >= tb.base[i]) s = i;
  transpose_tile_body(tb.src[s], tb.dst[s], tb.R[s], tb.C[s], bid - tb.base[s]);
}

// All-layer hoisted weight transpose: grid = NL*16384; blockIdx>>14 = layer.
// Per-layer slab layout (elems): [W3T 3dd | WoT dd | WgT dff | WuT dff | WdT dff]
__global__ void transpose_weights_all(
    const float* __restrict__ Wq, const float* __restrict__ Wk, const float* __restrict__ Wv,
    const float* __restrict__ Wo, const float* __restrict__ Wg, const float* __restrict__ Wu,
    const float* __restrict__ Wd, bf16* __restrict__ slab) {
  const int l = blockIdx.x >> 14;
  const int local = blockIdx.x & 16383;
  const size_t dd = (size_t)DIM * DIM, dff = (size_t)DIM * FFD;
  const size_t SL = 4 * dd + 3 * dff;
  const float* src;
  bf16* dst;
  int R, C, lb;
  if (local < 1024)      { lb = local;         R = DIM; C = DIM; src = Wq + l * dd;  dst = slab + l * SL; }
  else if (local < 2048) { lb = local - 1024;  R = DIM; C = DIM; src = Wk + l * dd;  dst = slab + l * SL + dd; }
  else if (local < 3072) { lb = local - 2048;  R = DIM; C = DIM; src = Wv + l * dd;  dst = slab + l * SL + 2 * dd; }
  else if (local < 4096) { lb = local - 3072;  R = DIM; C = DIM; src = Wo + l * dd;  dst = slab + l * SL + 3 * dd; }
  else if (local < 8192) { lb = local - 4096;  R = DIM; C = FFD; src = Wg + l * dff; dst = slab + l * SL + 4 * dd; }
  else if (local < 12288){ lb = local - 8192;  R = DIM; C = FFD; src = Wu + l * dff; dst = slab + l * SL + 4 * dd + dff; }
  else                   { lb = local - 12288; R = FFD; C = DIM; src = Wd + l * dff; dst = slab + l * SL + 4 * dd + 2 * dff; }
  transpose_tile_body(src, dst, R, C, lb);
}

// v [b*T+t][ldv stride, h*DH+dh] bf16 -> vT [(b*NH+h)*DH+dh][t] bf16
__global__ void transpose_v(const bf16* __restrict__ v, int ldv, bf16* __restrict__ vT) {
  __shared__ bf16 tile[32][33];
  int t0 = blockIdx.x * 32, d0 = blockIdx.y * 32, bh = blockIdx.z;
  int b = bh >> 4, h = bh & 15;
  int tx = threadIdx.x, ty = threadIdx.y;
#pragma unroll
  for (int i = 0; i < 4; ++i)
    tile[ty + i * 8][tx] = v[(size_t)(b * TT + t0 + ty + i * 8) * ldv + h * DH + d0 + tx];
  __syncthreads();
#pragma unroll
  for (int i = 0; i < 4; ++i)
    vT[((size_t)bh * DH + d0 + ty + i * 8) * TT + t0 + tx] = tile[tx][ty + i * 8];
}

// ---------------- embedding + rope ----------------

__global__ void embed_rope(const int* __restrict__ ids, const float* __restrict__ emb,
                           float* __restrict__ xf, bf16* __restrict__ xb) {
  int bt = blockIdx.x;
  int t = bt & (TT - 1);
  int id = ids[bt];
  const float* row = emb + (size_t)id * DIM;
  for (int p = threadIdx.x; p < DIM / 2; p += 256) {
    float x1 = row[2 * p], x2 = row[2 * p + 1];
    float inv = __expf(-9.210340371976184f * (float)p * (1.0f / 512.0f));
    float ang = (float)t * inv;
    float c = cosf(ang), s = sinf(ang);
    float o1 = x1 * c - x2 * s;
    float o2 = x1 * s + x2 * c;
    size_t base = (size_t)bt * DIM + 2 * p;
    xf[base] = o1; xf[base + 1] = o2;
    xb[base] = (bf16)o1; xb[base + 1] = (bf16)o2;
  }
}

enum { EP_BF16 = 0, EP_F32 = 1, EP_F32_BIAS = 2, EP_BF16_BIAS = 3, EP_SILU_MUL = 4 };

// ---------------- GEMM A: 256x256, 4-slot half-K ring, 512 thr (frozen) ----------------

template <int EP>
__global__ __launch_bounds__(512, 1) void gemm8(
    const bf16* __restrict__ A, const bf16* __restrict__ Bt, void* __restrict__ Cp,
    const float* __restrict__ bias, const bf16* __restrict__ aux,
    int M, int N, int K) {
  __shared__ bf16 S[4][2][256 * 32];   // [slot][A=0/B=1][256 rows x 32] = 128 KiB

  const int tid = threadIdx.x;
  const int lane = tid & 63;
  const int r16 = lane & 15, hi = lane >> 4;
  const int wave = tid >> 6;
  const int wm = wave >> 2, wn = wave & 3;

  const int nwg = gridDim.x;
  const int orig = blockIdx.x;
  const int qq = nwg >> 3, rr = nwg & 7;
  const int xcd = orig & 7, cidx = orig >> 3;
  const int wg = (xcd < rr ? xcd * (qq + 1) : rr * (qq + 1) + (xcd - rr) * qq) + cidx;
  const int gM = M / 256;
  const int m0 = (wg % gM) * 256;
  const int n0 = (wg / gM) * 256;

  const int srow = tid >> 2;               // 0..127
  const int ccol = tid & 3;
  const int skey = (srow >> 1) & 3;
  const int gcol = (ccol ^ skey) * 8;      // pre-swizzled global col
  const bf16* aS = A + (size_t)(m0 + srow) * K + gcol;
  const bf16* bS = Bt + (size_t)(n0 + srow) * K + gcol;
  const int dst0 = tid * 8;                // linear LDS dest

  const int rkey = (r16 >> 1) & 3;
  const int rchunk = (hi ^ rkey) * 8;

  f32x4 acc[8][4] = {};
  const int NT = K / 32;

#pragma unroll
  for (int s = 0; s < 3; ++s) {
    gld16(aS + s * 32, &S[s][0][dst0]);
    gld16(aS + s * 32 + (size_t)128 * K, &S[s][0][dst0 + 4096]);
    gld16(bS + s * 32, &S[s][1][dst0]);
    gld16(bS + s * 32 + (size_t)128 * K, &S[s][1][dst0 + 4096]);
  }
  asm volatile("s_waitcnt vmcnt(8)" ::: "memory");
  __builtin_amdgcn_s_barrier();
  __builtin_amdgcn_sched_barrier(0);

  for (int s = 0; s < NT; ++s) {
    const int cs = s & 3, ps = (s + 3) & 3;
    const bool pre = (s + 3) < NT;
    const bf16* SA = S[cs][0];
    const bf16* SB = S[cs][1];
    const size_t koff = (size_t)(s + 3) * 32;
    bf16x8 af[4], bfr[4];

#pragma unroll
    for (int j = 0; j < 4; ++j)
      bfr[j] = *(const bf16x8*)&SB[(wn * 64 + j * 16 + r16) * 32 + rchunk];
#pragma unroll
    for (int i = 0; i < 4; ++i)
      af[i] = *(const bf16x8*)&SA[(wm * 128 + i * 16 + r16) * 32 + rchunk];
    if (pre) {
      gld16(aS + koff, &S[ps][0][dst0]);
      gld16(aS + koff + (size_t)128 * K, &S[ps][0][dst0 + 4096]);
    }
    __builtin_amdgcn_s_barrier();
    __builtin_amdgcn_sched_barrier(0);
    __builtin_amdgcn_s_setprio(1);
#pragma unroll
    for (int i = 0; i < 4; ++i)
#pragma unroll
      for (int j = 0; j < 4; ++j)
        acc[i][j] = __builtin_amdgcn_mfma_f32_16x16x32_bf16(af[i], bfr[j], acc[i][j], 0, 0, 0);
    __builtin_amdgcn_s_setprio(0);
    __builtin_amdgcn_s_barrier();
    __builtin_amdgcn_sched_barrier(0);

#pragma unroll
    for (int i = 0; i < 4; ++i)
      af[i] = *(const bf16x8*)&SA[(wm * 128 + 64 + i * 16 + r16) * 32 + rchunk];
    if (pre) {
      gld16(bS + koff, &S[ps][1][dst0]);
      gld16(bS + koff + (size_t)128 * K, &S[ps][1][dst0 + 4096]);
    }
    __builtin_amdgcn_s_barrier();
    __builtin_amdgcn_sched_barrier(0);
    __builtin_amdgcn_s_setprio(1);
#pragma unroll
    for (int i = 0; i < 4; ++i)
#pragma unroll
      for (int j = 0; j < 4; ++j)
        acc[4 + i][j] = __builtin_amdgcn_mfma_f32_16x16x32_bf16(af[i], bfr[j], acc[4 + i][j], 0, 0, 0);
    __builtin_amdgcn_s_setprio(0);
    if (pre)               asm volatile("s_waitcnt vmcnt(8)" ::: "memory");
    else if ((s + 2) < NT) asm volatile("s_waitcnt vmcnt(4)" ::: "memory");
    else if ((s + 1) < NT) asm volatile("s_waitcnt vmcnt(0)" ::: "memory");
    __builtin_amdgcn_s_barrier();
    __builtin_amdgcn_sched_barrier(0);
  }

#pragma unroll
  for (int mi = 0; mi < 8; ++mi) {
    const int m = m0 + wm * 128 + mi * 16 + hi * 4;
#pragma unroll
    for (int j = 0; j < 4; ++j) {
      const int n = n0 + wn * 64 + j * 16 + r16;
#pragma unroll
      for (int q = 0; q < 4; ++q) {
        size_t idx = (size_t)(m + q) * N + n;
        float v = acc[mi][j][q];
        if constexpr (EP == EP_F32) {
          ((float*)Cp)[idx] = v;
        } else if constexpr (EP == EP_F32_BIAS) {
          ((float*)Cp)[idx] = v + bias[n];
        } else if constexpr (EP == EP_BF16) {
          ((bf16*)Cp)[idx] = (bf16)v;
        } else if constexpr (EP == EP_BF16_BIAS) {
          ((bf16*)Cp)[idx] = (bf16)(v + bias[n]);
        } else {
          float sg = v / (1.0f + __expf(-v));
          ((bf16*)Cp)[idx] = (bf16)(sg * (float)aux[idx]);
        }
      }
    }
  }
}

// ---------------- GEMM A-FF: fused dual-B (Wu,Wg) 256x128, silu epilogue ----------------

__global__ __launch_bounds__(512, 1) void gemm8ff(
    const bf16* __restrict__ A, const bf16* __restrict__ Bu, const bf16* __restrict__ Bg,
    bf16* __restrict__ Cp, int M, int N, int K) {
  __shared__ bf16 SA[4][256 * 32];   // 64 KiB
  __shared__ bf16 SU[4][128 * 32];   // 32 KiB
  __shared__ bf16 SG[4][128 * 32];   // 32 KiB

  const int tid = threadIdx.x;
  const int lane = tid & 63;
  const int r16 = lane & 15, hi = lane >> 4;
  const int wave = tid >> 6;
  const int wm = wave >> 2, wn = wave & 3;

  const int nwg = gridDim.x;
  const int orig = blockIdx.x;
  const int qq = nwg >> 3, rr = nwg & 7;
  const int xcd = orig & 7, cidx = orig >> 3;
  const int wg = (xcd < rr ? xcd * (qq + 1) : rr * (qq + 1) + (xcd - rr) * qq) + cidx;
  const int gM = M / 256;
  const int m0 = (wg % gM) * 256;
  const int n0 = (wg / gM) * 128;

  const int srow = tid >> 2;               // 0..127
  const int ccol = tid & 3;
  const int skey = (srow >> 1) & 3;
  const int gcol = (ccol ^ skey) * 8;
  const bf16* aS = A + (size_t)(m0 + srow) * K + gcol;
  const bf16* uS = Bu + (size_t)(n0 + srow) * K + gcol;
  const bf16* gSp = Bg + (size_t)(n0 + srow) * K + gcol;
  const int dst0 = tid * 8;

  const int rkey = (r16 >> 1) & 3;
  const int rchunk = (hi ^ rkey) * 8;

  f32x4 accU[8][2] = {}, accG[8][2] = {};
  const int NT = K / 32;

#pragma unroll
  for (int s = 0; s < 3; ++s) {
    gld16(aS + s * 32, &SA[s][dst0]);
    gld16(aS + s * 32 + (size_t)128 * K, &SA[s][dst0 + 4096]);
    gld16(uS + s * 32, &SU[s][dst0]);
    gld16(gSp + s * 32, &SG[s][dst0]);
  }
  asm volatile("s_waitcnt vmcnt(8)" ::: "memory");
  __builtin_amdgcn_s_barrier();
  __builtin_amdgcn_sched_barrier(0);

  for (int s = 0; s < NT; ++s) {
    const int cs = s & 3, ps = (s + 3) & 3;
    const bool pre = (s + 3) < NT;
    const size_t koff = (size_t)(s + 3) * 32;
    bf16x8 af[4], bu[2], bg[2];

#pragma unroll
    for (int j = 0; j < 2; ++j) {
      bu[j] = *(const bf16x8*)&SU[cs][(wn * 32 + j * 16 + r16) * 32 + rchunk];
      bg[j] = *(const bf16x8*)&SG[cs][(wn * 32 + j * 16 + r16) * 32 + rchunk];
    }
#pragma unroll
    for (int i = 0; i < 4; ++i)
      af[i] = *(const bf16x8*)&SA[cs][(wm * 128 + i * 16 + r16) * 32 + rchunk];
    if (pre) {
      gld16(aS + koff, &SA[ps][dst0]);
      gld16(aS + koff + (size_t)128 * K, &SA[ps][dst0 + 4096]);
    }
    __builtin_amdgcn_s_barrier();
    __builtin_amdgcn_sched_barrier(0);
    __builtin_amdgcn_s_setprio(1);
#pragma unroll
    for (int i = 0; i < 4; ++i)
#pragma unroll
      for (int j = 0; j < 2; ++j) {
        accU[i][j] = __builtin_amdgcn_mfma_f32_16x16x32_bf16(af[i], bu[j], accU[i][j], 0, 0, 0);
        accG[i][j] = __builtin_amdgcn_mfma_f32_16x16x32_bf16(af[i], bg[j], accG[i][j], 0, 0, 0);
      }
    __builtin_amdgcn_s_setprio(0);
    __builtin_amdgcn_s_barrier();
    __builtin_amdgcn_sched_barrier(0);

#pragma unroll
    for (int i = 0; i < 4; ++i)
      af[i] = *(const bf16x8*)&SA[cs][(wm * 128 + 64 + i * 16 + r16) * 32 + rchunk];
    if (pre) {
      gld16(uS + koff, &SU[ps][dst0]);
      gld16(gSp + koff, &SG[ps][dst0]);
    }
    __builtin_amdgcn_s_barrier();
    __builtin_amdgcn_sched_barrier(0);
    __builtin_amdgcn_s_setprio(1);
#pragma unroll
    for (int i = 0; i < 4; ++i)
#pragma unroll
      for (int j = 0; j < 2; ++j) {
        accU[4 + i][j] = __builtin_amdgcn_mfma_f32_16x16x32_bf16(af[i], bu[j], accU[4 + i][j], 0, 0, 0);
        accG[4 + i][j] = __builtin_amdgcn_mfma_f32_16x16x32_bf16(af[i], bg[j], accG[4 + i][j], 0, 0, 0);
      }
    __builtin_amdgcn_s_setprio(0);
    if (pre)               asm volatile("s_waitcnt vmcnt(8)" ::: "memory");
    else if ((s + 2) < NT) asm volatile("s_waitcnt vmcnt(4)" ::: "memory");
    else if ((s + 1) < NT) asm volatile("s_waitcnt vmcnt(0)" ::: "memory");
    __builtin_amdgcn_s_barrier();
    __builtin_amdgcn_sched_barrier(0);
  }

#pragma unroll
  for (int mi = 0; mi < 8; ++mi) {
    const int m = m0 + wm * 128 + mi * 16 + hi * 4;
#pragma unroll
    for (int j = 0; j < 2; ++j) {
      const int n = n0 + wn * 32 + j * 16 + r16;
#pragma unroll
      for (int q = 0; q < 4; ++q) {
        float u = accU[mi][j][q];
        float g = accG[mi][j][q];
        float sg = g / (1.0f + __expf(-g));
        Cp[(size_t)(m + q) * N + n] = (bf16)(sg * u);
      }
    }
  }
}

// ---------------- GEMM B: BMxBN ring (generalized; LA/LB staging passes) ----------------

template <int BM, int BN, int WMW, int WNW, int EP>
__global__ __launch_bounds__(WMW * WNW * 64, 2) void gemmk(
    const bf16* __restrict__ A, const bf16* __restrict__ Bt, void* __restrict__ Cp,
    const float* __restrict__ bias, const bf16* __restrict__ aux,
    int M, int N, int K) {
  constexpr int BK = 32;
  constexpr int MF = BM / (WMW * 16);
  constexpr int NF = BN / (WNW * 16);
  constexpr int LA = BM / 64;
  constexpr int LB = BN / 64;
  constexpr int VM_MAIN = 2 * LA + LB;
  constexpr int VM_TAIL = LA + LB;
  __shared__ bf16 sA[4][BM * BK];
  __shared__ bf16 sB[4][BN * BK];

  const int tid = threadIdx.x;
  const int lane = tid & 63;
  const int r16 = lane & 15, hi = lane >> 4;
  const int wave = tid >> 6;
  const int wm = wave / WNW, wn = wave % WNW;

  const int nwg = gridDim.x;
  const int orig = blockIdx.x;
  const int qq = nwg >> 3, rr = nwg & 7;
  const int xcd = orig & 7, cidx = orig >> 3;
  const int wg = (xcd < rr ? xcd * (qq + 1) : rr * (qq + 1) + (xcd - rr) * qq) + cidx;
  const int gM = M / BM;
  const int m0 = (wg % gM) * BM;
  const int n0 = (wg / gM) * BN;

  const int srow = tid >> 2;
  const int ccol = tid & 3;
  const int skey = (srow >> 1) & 3;
  const int gcol = ((ccol ^ skey)) * 8;
  const bf16* aS = A + (size_t)(m0 + srow) * K + gcol;
  const bf16* bS = Bt + (size_t)(n0 + srow) * K + gcol;
  const int dst0 = srow * BK + ccol * 8;

  const int rkey = (r16 >> 1) & 3;
  const int rchunk = (hi ^ rkey) * 8;

  f32x4 acc[MF][NF] = {};
  const int NT = K / BK;

#pragma unroll
  for (int t0_ = 0; t0_ < 2; ++t0_) {
#pragma unroll
    for (int p = 0; p < LA; ++p)
      gld16(aS + t0_ * BK + (size_t)p * 64 * K, &sA[t0_][dst0 + p * 64 * BK]);
#pragma unroll
    for (int p = 0; p < LB; ++p)
      gld16(bS + t0_ * BK + (size_t)p * 64 * K, &sB[t0_][dst0 + p * 64 * BK]);
  }

  for (int t = 0; t < NT; ++t) {
    const int cb = t & 3;
    const int pb = (t + 2) & 3;
    const bool pre = (t + 2) < NT;
    if (pre) {
#pragma unroll
      for (int p = 0; p < LA; ++p)
        gld16(aS + (size_t)(t + 2) * BK + (size_t)p * 64 * K, &sA[pb][dst0 + p * 64 * BK]);
    }
    if (pre)             asm volatile("s_waitcnt vmcnt(%0)" :: "i"(VM_MAIN) : "memory");
    else if (t + 1 < NT) asm volatile("s_waitcnt vmcnt(%0)" :: "i"(VM_TAIL) : "memory");
    else                 asm volatile("s_waitcnt vmcnt(0)" ::: "memory");
    __builtin_amdgcn_s_barrier();
    __builtin_amdgcn_sched_barrier(0);

    bf16x8 bf_[NF];
#pragma unroll
    for (int j = 0; j < NF; ++j)
      bf_[j] = *(const bf16x8*)&sB[cb][(wn * (NF * 16) + j * 16 + r16) * BK + rchunk];
    if (pre) {
#pragma unroll
      for (int p = 0; p < LB; ++p)
        gld16(bS + (size_t)(t + 2) * BK + (size_t)p * 64 * K, &sB[pb][dst0 + p * 64 * BK]);
    }
    bf16x8 af[MF];
#pragma unroll
    for (int i = 0; i < MF; ++i)
      af[i] = *(const bf16x8*)&sA[cb][(wm * (MF * 16) + i * 16 + r16) * BK + rchunk];
    __builtin_amdgcn_s_setprio(1);
#pragma unroll
    for (int i = 0; i < MF; ++i)
#pragma unroll
      for (int j = 0; j < NF; ++j)
        acc[i][j] = __builtin_amdgcn_mfma_f32_16x16x32_bf16(af[i], bf_[j], acc[i][j], 0, 0, 0);
    __builtin_amdgcn_s_setprio(0);
  }

#pragma unroll
  for (int i = 0; i < MF; ++i) {
    const int m = m0 + wm * (MF * 16) + i * 16 + hi * 4;
#pragma unroll
    for (int j = 0; j < NF; ++j) {
      const int n = n0 + wn * (NF * 16) + j * 16 + r16;
#pragma unroll
      for (int q = 0; q < 4; ++q) {
        size_t idx = (size_t)(m + q) * N + n;
        float v = acc[i][j][q];
        if constexpr (EP == EP_F32) {
          ((float*)Cp)[idx] = v;
        } else if constexpr (EP == EP_F32_BIAS) {
          ((float*)Cp)[idx] = v + bias[n];
        } else if constexpr (EP == EP_BF16) {
          ((bf16*)Cp)[idx] = (bf16)v;
        } else if constexpr (EP == EP_BF16_BIAS) {
          ((bf16*)Cp)[idx] = (bf16)(v + bias[n]);
        } else {
          float sg = v / (1.0f + __expf(-v));
          ((bf16*)Cp)[idx] = (bf16)(sg * (float)aux[idx]);
        }
      }
    }
  }
}

// ---------------- flash attention: swapped QK^T, QBLK=128 (2 Q-frags/wave) ----------------

__global__ __launch_bounds__(256, 2) void attn_flash(
    const bf16* __restrict__ Qp, const bf16* __restrict__ Kp, int ldk,
    const bf16* __restrict__ Vt, bf16* __restrict__ Op) {
  __shared__ bf16 Ks[2][128 * 32];
  __shared__ bf16 Vs[4][64 * 32];
  __shared__ bf16 Ps[4][2][16 * 144];
  const int tid = threadIdx.x, lane = tid & 63, wave = tid >> 6;
  const int h = blockIdx.y, b = blockIdx.z;
  const int r16 = lane & 15, hi = lane >> 4;
  const int qbase = blockIdx.x * 128 + wave * 32;

  const float QS = 0.1803368801f;          // 0.125 * log2(e)
  bf16x8 qa[2][2];
#pragma unroll
  for (int f = 0; f < 2; ++f) {
    const bf16* qp = Qp + (size_t)(b * TT + qbase + f * 16 + r16) * ldk + h * DH + hi * 8;
    bf16x8 q0 = *(const bf16x8*)qp;
    bf16x8 q1 = *(const bf16x8*)(qp + 32);
#pragma unroll
    for (int e = 0; e < 8; ++e) {
      qa[f][0][e] = (bf16)((float)q0[e] * QS);
      qa[f][1][e] = (bf16)((float)q1[e] * QS);
    }
  }
  const bf16* kBase = Kp + (size_t)(b * TT) * ldk + h * DH;
  const bf16* vBase = Vt + (size_t)(b * NH + h) * DH * TT;

  const int srow = tid >> 2, ccol = tid & 3;
  const int skey = (srow >> 1) & 3;
  const int scolS = (ccol ^ skey) * 8;
  const int dstc = ccol * 8;
  const int rkey = (r16 >> 1) & 3;
  const int rchunk = (hi ^ rkey) * 8;

  float m_run[2] = {-1e30f, -1e30f};
  float l_run[2] = {0.f, 0.f};
  f32x4 oacc[2][4] = {};

  for (int kt = 0; kt < TT; kt += 128) {
#pragma unroll
    for (int half = 0; half < 2; ++half) {
      gld16(kBase + (size_t)(kt + srow) * ldk + half * 32 + scolS, &Ks[half][srow * 32 + dstc]);
      gld16(kBase + (size_t)(kt + 64 + srow) * ldk + half * 32 + scolS, &Ks[half][(64 + srow) * 32 + dstc]);
    }
#pragma unroll
    for (int ks = 0; ks < 4; ++ks)
      gld16(vBase + (size_t)srow * TT + kt + ks * 32 + scolS, &Vs[ks][srow * 32 + dstc]);
    __syncthreads();

#pragma unroll
    for (int f = 0; f < 2; ++f) {
      f32x4 s[8];
      __builtin_amdgcn_s_setprio(1);
#pragma unroll
      for (int kg = 0; kg < 8; ++kg) {
        f32x4 z = {};
        bf16x8 kb0 = *(const bf16x8*)&Ks[0][(kg * 16 + r16) * 32 + rchunk];
        bf16x8 kb1 = *(const bf16x8*)&Ks[1][(kg * 16 + r16) * 32 + rchunk];
        z = __builtin_amdgcn_mfma_f32_16x16x32_bf16(kb0, qa[f][0], z, 0, 0, 0);
        z = __builtin_amdgcn_mfma_f32_16x16x32_bf16(kb1, qa[f][1], z, 0, 0, 0);
        s[kg] = z;
      }
      __builtin_amdgcn_s_setprio(0);

      float pm = s[0][0];
#pragma unroll
      for (int kg = 0; kg < 8; ++kg)
#pragma unroll
        for (int i = 0; i < 4; ++i) pm = fmaxf(pm, s[kg][i]);
      pm = fmaxf(pm, __shfl_xor(pm, 16));
      pm = fmaxf(pm, __shfl_xor(pm, 32));

      if (!__all(pm - m_run[f] <= 11.5411f)) {
        float mnew = fmaxf(m_run[f], pm);
        float fr = exp2f(m_run[f] - mnew);
        m_run[f] = mnew;
        l_run[f] *= fr;
#pragma unroll
        for (int i = 0; i < 4; ++i) {
          float fi = __shfl(fr, hi * 4 + i);
#pragma unroll
          for (int n = 0; n < 4; ++n) oacc[f][n][i] *= fi;
        }
      }

      float lsum = 0.f;
#pragma unroll
      for (int kg = 0; kg < 8; ++kg) {
        float p0 = exp2f(s[kg][0] - m_run[f]);
        float p1 = exp2f(s[kg][1] - m_run[f]);
        float p2 = exp2f(s[kg][2] - m_run[f]);
        float p3 = exp2f(s[kg][3] - m_run[f]);
        lsum += (p0 + p1) + (p2 + p3);
        bf16x4 pk = {(bf16)p0, (bf16)p1, (bf16)p2, (bf16)p3};
        *(bf16x4*)&Ps[wave][f][r16 * 144 + kg * 16 + hi * 4] = pk;
      }
      l_run[f] += lsum;

      __builtin_amdgcn_s_setprio(1);
#pragma unroll
      for (int ks = 0; ks < 4; ++ks) {
        bf16x8 pa = *(const bf16x8*)&Ps[wave][f][r16 * 144 + ks * 32 + hi * 8];
#pragma unroll
        for (int n = 0; n < 4; ++n) {
          bf16x8 vb = *(const bf16x8*)&Vs[ks][(n * 16 + r16) * 32 + rchunk];
          oacc[f][n] = __builtin_amdgcn_mfma_f32_16x16x32_bf16(pa, vb, oacc[f][n], 0, 0, 0);
        }
      }
      __builtin_amdgcn_s_setprio(0);
    }
    __syncthreads();
  }

#pragma unroll
  for (int f = 0; f < 2; ++f) {
    float lq = l_run[f];
    lq += __shfl_xor(lq, 16);
    lq += __shfl_xor(lq, 32);
    float invq = 1.0f / lq;
#pragma unroll
    for (int i = 0; i < 4; ++i) {
      float inv_i = __shfl(invq, hi * 4 + i);
      int trow = qbase + f * 16 + hi * 4 + i;
      size_t base = ((size_t)b * TT + trow) * DIM + h * DH;
#pragma unroll
      for (int n = 0; n < 4; ++n)
        Op[base + n * 16 + r16] = (bf16)(oacc[f][n][i] * inv_i);
    }
  }
}

// ---------------- residual + rmsnorm ----------------

__global__ __launch_bounds__(256) void resid_rms(
    const float* __restrict__ xin, const float* __restrict__ y, const float* __restrict__ wgt,
    float* __restrict__ xf_out, bf16* __restrict__ xb_out) {
  __shared__ float red[4];
  const int r = blockIdx.x, tid = threadIdx.x;
  const size_t base = (size_t)r * DIM + tid * 4;
  float4 v = *(const float4*)(xin + base);
  float4 u = *(const float4*)(y + base);
  v.x += u.x; v.y += u.y; v.z += u.z; v.w += u.w;
  float ss = v.x * v.x + v.y * v.y + v.z * v.z + v.w * v.w;
#pragma unroll
  for (int d = 1; d < 64; d <<= 1) ss += __shfl_xor(ss, d);
  if ((tid & 63) == 0) red[tid >> 6] = ss;
  __syncthreads();
  ss = red[0] + red[1] + red[2] + red[3];
  float sc = rsqrtf(ss * (1.0f / DIM) + 1e-8f);
  const float4 wv = *(const float4*)(wgt + tid * 4);
  float o0 = v.x * sc * wv.x, o1 = v.y * sc * wv.y, o2 = v.z * sc * wv.z, o3 = v.w * sc * wv.w;
  if (xf_out) {
    float4 ov = {o0, o1, o2, o3};
    *(float4*)(xf_out + base) = ov;
  }
  bf16x4 ob = {(bf16)o0, (bf16)o1, (bf16)o2, (bf16)o3};
  *(bf16x4*)(xb_out + base) = ob;
}

// ---------------- slot softmax rows (scale D^-0.5 = 1/32) ----------------

__global__ __launch_bounds__(256) void softmax_rows(const float* __restrict__ Sc, bf16* __restrict__ P) {
  __shared__ float red[4];
  const int r = blockIdx.x, tid = threadIdx.x;
  const float* row = Sc + (size_t)r * NSLOT;
  float4 v[4];
#pragma unroll
  for (int i = 0; i < 4; ++i) v[i] = *(const float4*)(row + tid * 4 + i * 1024);
  float mx = -1e30f;
#pragma unroll
  for (int i = 0; i < 4; ++i)
    mx = fmaxf(fmaxf(fmaxf(fmaxf(mx, v[i].x), v[i].y), v[i].z), v[i].w);
#pragma unroll
  for (int d = 1; d < 64; d <<= 1) mx = fmaxf(mx, __shfl_xor(mx, d));
  if ((tid & 63) == 0) red[tid >> 6] = mx;
  __syncthreads();
  mx = fmaxf(fmaxf(red[0], red[1]), fmaxf(red[2], red[3]));
  __syncthreads();
  float e[16];
  float sum = 0.f;
#pragma unroll
  for (int i = 0; i < 4; ++i) {
    e[i * 4 + 0] = __expf((v[i].x - mx) * 0.03125f);
    e[i * 4 + 1] = __expf((v[i].y - mx) * 0.03125f);
    e[i * 4 + 2] = __expf((v[i].z - mx) * 0.03125f);
    e[i * 4 + 3] = __expf((v[i].w - mx) * 0.03125f);
    sum += e[i * 4 + 0] + e[i * 4 + 1] + e[i * 4 + 2] + e[i * 4 + 3];
  }
#pragma unroll
  for (int d = 1; d < 64; d <<= 1) sum += __shfl_xor(sum, d);
  if ((tid & 63) == 0) red[tid >> 6] = sum;
  __syncthreads();
  sum = red[0] + red[1] + red[2] + red[3];
  float inv = 1.0f / sum;
#pragma unroll
  for (int i = 0; i < 4; ++i) {
    bf16x4 ob = {(bf16)(e[i * 4 + 0] * inv), (bf16)(e[i * 4 + 1] * inv),
                 (bf16)(e[i * 4 + 2] * inv), (bf16)(e[i * 4 + 3] * inv)};
    *(bf16x4*)(P + (size_t)r * NSLOT + tid * 4 + i * 1024) = ob;
  }
}

// ---------------- host orchestration ----------------

extern "C" void kernel_launch(void* const* d_in, const int* in_sizes, int n_in,
                              void* d_out, int out_size, void* d_ws, size_t ws_size,
                              hipStream_t stream) {
  (void)in_sizes; (void)n_in; (void)out_size;
  const int* ids = (const int*)d_in[0];
  const float* emb = (const float*)d_in[1];
  const float* Wq = (const float*)d_in[2];
  const float* Wk = (const float*)d_in[3];
  const float* Wv = (const float*)d_in[4];
  const float* Wo = (const float*)d_in[5];
  const float* bo = (const float*)d_in[6];
  const float* n1 = (const float*)d_in[7];
  const float* Wg = (const float*)d_in[8];
  const float* Wu = (const float*)d_in[9];
  const float* Wd = (const float*)d_in[10];
  const float* n2 = (const float*)d_in[11];
  const float* memp = (const float*)d_in[12];
  const float* Wsp = (const float*)d_in[13];
  const float* bsp = (const float*)d_in[14];
  const float* Wrp = (const float*)d_in[15];
  const float* brp = (const float*)d_in[16];
  const float* nout = (const float*)d_in[17];

  char* w = (char*)d_ws;
  auto alloc = [&](size_t bytes) -> void* {
    void* p = (void*)w;
    w += (bytes + 255) & ~(size_t)255;
    return p;
  };

  const size_t dd = (size_t)DIM * DIM;
  const size_t dff = (size_t)DIM * FFD;
  const size_t SL = 4 * dd + 3 * dff;       // per-layer transposed-weight slab (elems)

  bf16* tok_b = (bf16*)alloc((size_t)NV * DIM * 2);
  bf16* mem_b = (bf16*)alloc((size_t)NSLOT * DIM * 2);
  bf16* memT  = (bf16*)alloc((size_t)NSLOT * DIM * 2);
  bf16* WspT  = (bf16*)alloc(dd * 2);
  bf16* WrpT  = (bf16*)alloc(dd * 2);
  float* xf   = (float*)alloc((size_t)BT * DIM * 4);
  bf16* xb    = (bf16*)alloc((size_t)BT * DIM * 2);
  float* yb   = (float*)alloc((size_t)BT * DIM * 4);
  bf16* qkv   = (bf16*)alloc((size_t)BT * 3 * DIM * 2);
  bf16* vT_   = (bf16*)alloc((size_t)BT * DIM * 2);
  bf16* ot_   = (bf16*)alloc((size_t)BT * DIM * 2);
  bf16* qb    = (bf16*)alloc((size_t)BT * DIM * 2);
  bf16* rb    = (bf16*)alloc((size_t)BT * DIM * 2);
  bf16* hb    = (bf16*)alloc((size_t)BT * DIM * 2);

  // Region for FF activations / slot scores (overlay; may fall back to d_out)
  // and, if space permits, the hoisted all-layer weight slab.
  size_t used0 = (size_t)(w - (char*)d_ws);
  size_t region_bytes = (size_t)BT * NSLOT * 4 + (size_t)BT * NSLOT * 2;
  size_t slab_bytes = (size_t)NL * SL * 2;
  size_t fallback_bytes = SL * 2;           // single-layer buffers if no hoist

  bool hoist = (used0 + slab_bytes + region_bytes) <= ws_size;
  bf16* slab = nullptr;
  bf16* W3T = nullptr; bf16* WoT = nullptr; bf16* WgT = nullptr; bf16* WuT = nullptr; bf16* WdT = nullptr;
  if (hoist) {
    slab = (bf16*)alloc(slab_bytes);
  } else {
    bf16* single = (bf16*)alloc(fallback_bytes);
    W3T = single;                 // 3*dd
    WoT = single + 3 * dd;        // dd
    WgT = single + 4 * dd;        // dff
    WuT = single + 4 * dd + dff;  // dff
    WdT = single + 4 * dd + 2 * dff;
  }

  size_t used = (size_t)(w - (char*)d_ws);
  char* region;
  if (used + region_bytes <= ws_size) region = (char*)alloc(region_bytes);
  else region = (char*)d_out;  // only written mid-pipeline, d_out rewritten at end
  bf16* Hb = (bf16*)region;
  float* scoresF = (float*)region;
  bf16* attnb = (bf16*)(region + (size_t)BT * NSLOT * 4);

  dim3 blkT(8, 32);
  dim3 blkV(32, 8);

  cvt_bf16<<<NV * DIM / 1024, 256, 0, stream>>>(emb, tok_b, (long)NV * DIM);
  cvt_bf16<<<NSLOT * DIM / 1024, 256, 0, stream>>>(memp, mem_b, (long)NSLOT * DIM);
  {
    TBatch tb{};
    tb.src[0] = memp; tb.dst[0] = memT; tb.R[0] = NSLOT; tb.C[0] = DIM; tb.base[0] = 0;
    tb.src[1] = Wsp;  tb.dst[1] = WspT; tb.R[1] = DIM;   tb.C[1] = DIM; tb.base[1] = 4096;
    tb.src[2] = Wrp;  tb.dst[2] = WrpT; tb.R[2] = DIM;   tb.C[2] = DIM; tb.base[2] = 5120;
    for (int i = 3; i < 7; ++i) { tb.base[i] = 0x7fffffff; tb.src[i] = memp; tb.dst[i] = memT; tb.R[i] = 32; tb.C[i] = 32; }
    transpose_cvt_batch<<<6144, blkT, 0, stream>>>(tb);
  }
  if (hoist) {
    transpose_weights_all<<<NL * 16384, blkT, 0, stream>>>(Wq, Wk, Wv, Wo, Wg, Wu, Wd, slab);
  }
  embed_rope<<<BT, 256, 0, stream>>>(ids, emb, xf, xb);

  for (int l = 0; l < NL; ++l) {
    const bf16 *w3t, *wot, *wgt2, *wut, *wdt;
    if (hoist) {
      bf16* s = slab + (size_t)l * SL;
      w3t = s; wot = s + 3 * dd; wgt2 = s + 4 * dd; wut = s + 4 * dd + dff; wdt = s + 4 * dd + 2 * dff;
    } else {
      TBatch tb{};
      tb.src[0] = Wq + l * dd;  tb.dst[0] = W3T;          tb.R[0] = DIM; tb.C[0] = DIM;  tb.base[0] = 0;
      tb.src[1] = Wk + l * dd;  tb.dst[1] = W3T + dd;     tb.R[1] = DIM; tb.C[1] = DIM;  tb.base[1] = 1024;
      tb.src[2] = Wv + l * dd;  tb.dst[2] = W3T + 2 * dd; tb.R[2] = DIM; tb.C[2] = DIM;  tb.base[2] = 2048;
      tb.src[3] = Wo + l * dd;  tb.dst[3] = WoT;          tb.R[3] = DIM; tb.C[3] = DIM;  tb.base[3] = 3072;
      tb.src[4] = Wg + l * dff; tb.dst[4] = WgT;          tb.R[4] = DIM; tb.C[4] = FFD;  tb.base[4] = 4096;
      tb.src[5] = Wu + l * dff; tb.dst[5] = WuT;          tb.R[5] = DIM; tb.C[5] = FFD;  tb.base[5] = 8192;
      tb.src[6] = Wd + l * dff; tb.dst[6] = WdT;          tb.R[6] = FFD; tb.C[6] = DIM;  tb.base[6] = 12288;
      transpose_cvt_batch<<<16384, blkT, 0, stream>>>(tb);
      w3t = W3T; wot = WoT; wgt2 = WgT; wut = WuT; wdt = WdT;
    }

    gemm8<EP_BF16><<<dim3(16 * 12), 512, 0, stream>>>(
        xb, w3t, qkv, nullptr, nullptr, BT, 3 * DIM, DIM);
    transpose_v<<<dim3(TT / 32, DH / 32, BB * NH), blkV, 0, stream>>>(qkv + 2 * DIM, 3 * DIM, vT_);
    attn_flash<<<dim3(TT / 128, NH, BB), 256, 0, stream>>>(qkv, qkv + DIM, 3 * DIM, vT_, ot_);
    gemmk<128, 64, 2, 2, EP_F32_BIAS><<<dim3(32 * 16), 256, 0, stream>>>(
        ot_, wot, yb, bo + l * DIM, nullptr, BT, DIM, DIM);
    resid_rms<<<BT, 256, 0, stream>>>(xf, yb, n1 + l * DIM, xf, xb);
    gemm8ff<<<dim3(16 * 32), 512, 0, stream>>>(
        xb, wut, wgt2, Hb, BT, FFD, DIM);
    gemmk<128, 64, 2, 2, EP_F32><<<dim3(32 * 16), 256, 0, stream>>>(
        Hb, wdt, yb, nullptr, nullptr, BT, DIM, FFD);
    resid_rms<<<BT, 256, 0, stream>>>(xf, yb, n2 + l * DIM, xf, xb);
  }

  gemmk<128, 64, 2, 2, EP_BF16_BIAS><<<dim3(32 * 16), 256, 0, stream>>>(
      xb, WspT, qb, bsp, nullptr, BT, DIM, DIM);
  gemm8<EP_F32><<<dim3(16 * 16), 512, 0, stream>>>(
      qb, mem_b, scoresF, nullptr, nullptr, BT, NSLOT, DIM);
  softmax_rows<<<BT, 256, 0, stream>>>(scoresF, attnb);
  gemmk<128, 64, 2, 2, EP_BF16><<<dim3(32 * 16), 256, 0, stream>>>(
      attnb, memT, rb, nullptr, nullptr, BT, DIM, NSLOT);
  gemmk<128, 64, 2, 2, EP_F32_BIAS><<<dim3(32 * 16), 256, 0, stream>>>(
      rb, WrpT, yb, brp, nullptr, BT, DIM, DIM);
  resid_rms<<<BT, 256, 0, stream>>>(xf, yb, nout, nullptr, hb);
  gemm8<EP_F32><<<dim3(16 * 125), 512, 0, stream>>>(
      hb, tok_b, (float*)d_out, nullptr, nullptr, BT, NV, DIM);
}

// Round 14
// 2638.469 us; speedup vs baseline: 1.0599x; 1.0599x over previous
//
#include <hip/hip_runtime.h>

typedef __bf16 bf16;
typedef __attribute__((ext_vector_type(8))) __bf16 bf16x8;
typedef __attribute__((ext_vector_type(4))) __bf16 bf16x4;
typedef __attribute__((ext_vector_type(4))) float f32x4;

#define NL 6
#define DIM 1024
#define NH 16
#define DH 64
#define TT 2048
#define BB 2
#define BT 4096
#define FFD 4096
#define NSLOT 4096
#define NV 32000

__device__ __forceinline__ void gld16(const void* g, void* l) {
  __builtin_amdgcn_global_load_lds(
      (const __attribute__((address_space(1))) void*)g,
      (__attribute__((address_space(3))) void*)l, 16, 0, 0);
}

// ---------------- conversion / transpose kernels ----------------

__global__ void cvt_bf16(const float* __restrict__ s, bf16* __restrict__ d, long n) {
  long i = ((long)blockIdx.x * 256 + threadIdx.x) * 4;
  if (i + 3 < n) {
    float4 v = *(const float4*)(s + i);
    bf16x4 o = {(bf16)v.x, (bf16)v.y, (bf16)v.z, (bf16)v.w};
    *(bf16x4*)(d + i) = o;
  }
}

// Batched transpose: up to 7 segments in one launch (verified R12 body).
// NOTE (R13 lesson): keep per-layer (not hoisted) — the transpose doubles as
// an L3 prefetch of the layer's weights; hoisting all layers evicts and
// forces cold HBM weight reads (+163 us measured).
struct TBatch {
  const float* src[7];
  bf16* dst[7];
  int R[7], C[7];
  int base[7];
};

__global__ void transpose_cvt_batch(TBatch tb) {
  const int bid = blockIdx.x;
  int s = 0;
#pragma unroll
  for (int i = 1; i < 7; ++i)
    if (bid >= tb.base[i]) s = i;
  const int local = bid - tb.base[s];
  const int R = tb.R[s], C = tb.C[s];
  const float* __restrict__ src = tb.src[s];
  bf16* __restrict__ dst = tb.dst[s];
  const int tilesPerRow = C / 32;
  const int c0 = (local % tilesPerRow) * 32;
  const int r0 = (local / tilesPerRow) * 32;

  __shared__ float tile[32][33];
  int tx = threadIdx.x;  // 0..7
  int ty = threadIdx.y;  // 0..31
  float4 v = *(const float4*)(src + (size_t)(r0 + ty) * C + c0 + tx * 4);
  tile[ty][tx * 4 + 0] = v.x;
  tile[ty][tx * 4 + 1] = v.y;
  tile[ty][tx * 4 + 2] = v.z;
  tile[ty][tx * 4 + 3] = v.w;
  __syncthreads();
  bf16x4 o = {(bf16)tile[tx * 4 + 0][ty], (bf16)tile[tx * 4 + 1][ty],
              (bf16)tile[tx * 4 + 2][ty], (bf16)tile[tx * 4 + 3][ty]};
  *(bf16x4*)(dst + (size_t)(c0 + ty) * R + r0 + tx * 4) = o;
}

// v [b*T+t][ldv stride, h*DH+dh] bf16 -> vT [(b*NH+h)*DH+dh][t] bf16
__global__ void transpose_v(const bf16* __restrict__ v, int ldv, bf16* __restrict__ vT) {
  __shared__ bf16 tile[32][33];
  int t0 = blockIdx.x * 32, d0 = blockIdx.y * 32, bh = blockIdx.z;
  int b = bh >> 4, h = bh & 15;
  int tx = threadIdx.x, ty = threadIdx.y;
#pragma unroll
  for (int i = 0; i < 4; ++i)
    tile[ty + i * 8][tx] = v[(size_t)(b * TT + t0 + ty + i * 8) * ldv + h * DH + d0 + tx];
  __syncthreads();
#pragma unroll
  for (int i = 0; i < 4; ++i)
    vT[((size_t)bh * DH + d0 + ty + i * 8) * TT + t0 + tx] = tile[tx][ty + i * 8];
}

// ---------------- embedding + rope ----------------

__global__ void embed_rope(const int* __restrict__ ids, const float* __restrict__ emb,
                           float* __restrict__ xf, bf16* __restrict__ xb) {
  int bt = blockIdx.x;
  int t = bt & (TT - 1);
  int id = ids[bt];
  const float* row = emb + (size_t)id * DIM;
  for (int p = threadIdx.x; p < DIM / 2; p += 256) {
    float x1 = row[2 * p], x2 = row[2 * p + 1];
    float inv = __expf(-9.210340371976184f * (float)p * (1.0f / 512.0f));
    float ang = (float)t * inv;
    float c = cosf(ang), s = sinf(ang);
    float o1 = x1 * c - x2 * s;
    float o2 = x1 * s + x2 * c;
    size_t base = (size_t)bt * DIM + 2 * p;
    xf[base] = o1; xf[base + 1] = o2;
    xb[base] = (bf16)o1; xb[base + 1] = (bf16)o2;
  }
}

enum { EP_BF16 = 0, EP_F32 = 1, EP_F32_BIAS = 2, EP_BF16_BIAS = 3, EP_SILU_MUL = 4 };

// ---------------- GEMM A: 256x256, 4-slot half-K ring, 512 thr (frozen) ----------------

template <int EP>
__global__ __launch_bounds__(512, 1) void gemm8(
    const bf16* __restrict__ A, const bf16* __restrict__ Bt, void* __restrict__ Cp,
    const float* __restrict__ bias, const bf16* __restrict__ aux,
    int M, int N, int K) {
  __shared__ bf16 S[4][2][256 * 32];   // [slot][A=0/B=1][256 rows x 32] = 128 KiB

  const int tid = threadIdx.x;
  const int lane = tid & 63;
  const int r16 = lane & 15, hi = lane >> 4;
  const int wave = tid >> 6;
  const int wm = wave >> 2, wn = wave & 3;

  const int nwg = gridDim.x;
  const int orig = blockIdx.x;
  const int qq = nwg >> 3, rr = nwg & 7;
  const int xcd = orig & 7, cidx = orig >> 3;
  const int wg = (xcd < rr ? xcd * (qq + 1) : rr * (qq + 1) + (xcd - rr) * qq) + cidx;
  const int gM = M / 256;
  const int m0 = (wg % gM) * 256;
  const int n0 = (wg / gM) * 256;

  const int srow = tid >> 2;               // 0..127
  const int ccol = tid & 3;
  const int skey = (srow >> 1) & 3;
  const int gcol = (ccol ^ skey) * 8;      // pre-swizzled global col
  const bf16* aS = A + (size_t)(m0 + srow) * K + gcol;
  const bf16* bS = Bt + (size_t)(n0 + srow) * K + gcol;
  const int dst0 = tid * 8;                // linear LDS dest

  const int rkey = (r16 >> 1) & 3;
  const int rchunk = (hi ^ rkey) * 8;

  f32x4 acc[8][4] = {};
  const int NT = K / 32;

#pragma unroll
  for (int s = 0; s < 3; ++s) {
    gld16(aS + s * 32, &S[s][0][dst0]);
    gld16(aS + s * 32 + (size_t)128 * K, &S[s][0][dst0 + 4096]);
    gld16(bS + s * 32, &S[s][1][dst0]);
    gld16(bS + s * 32 + (size_t)128 * K, &S[s][1][dst0 + 4096]);
  }
  asm volatile("s_waitcnt vmcnt(8)" ::: "memory");
  __builtin_amdgcn_s_barrier();
  __builtin_amdgcn_sched_barrier(0);

  for (int s = 0; s < NT; ++s) {
    const int cs = s & 3, ps = (s + 3) & 3;
    const bool pre = (s + 3) < NT;
    const bf16* SA = S[cs][0];
    const bf16* SB = S[cs][1];
    const size_t koff = (size_t)(s + 3) * 32;
    bf16x8 af[4], bfr[4];

#pragma unroll
    for (int j = 0; j < 4; ++j)
      bfr[j] = *(const bf16x8*)&SB[(wn * 64 + j * 16 + r16) * 32 + rchunk];
#pragma unroll
    for (int i = 0; i < 4; ++i)
      af[i] = *(const bf16x8*)&SA[(wm * 128 + i * 16 + r16) * 32 + rchunk];
    if (pre) {
      gld16(aS + koff, &S[ps][0][dst0]);
      gld16(aS + koff + (size_t)128 * K, &S[ps][0][dst0 + 4096]);
    }
    __builtin_amdgcn_s_barrier();
    __builtin_amdgcn_sched_barrier(0);
    __builtin_amdgcn_s_setprio(1);
#pragma unroll
    for (int i = 0; i < 4; ++i)
#pragma unroll
      for (int j = 0; j < 4; ++j)
        acc[i][j] = __builtin_amdgcn_mfma_f32_16x16x32_bf16(af[i], bfr[j], acc[i][j], 0, 0, 0);
    __builtin_amdgcn_s_setprio(0);
    __builtin_amdgcn_s_barrier();
    __builtin_amdgcn_sched_barrier(0);

#pragma unroll
    for (int i = 0; i < 4; ++i)
      af[i] = *(const bf16x8*)&SA[(wm * 128 + 64 + i * 16 + r16) * 32 + rchunk];
    if (pre) {
      gld16(bS + koff, &S[ps][1][dst0]);
      gld16(bS + koff + (size_t)128 * K, &S[ps][1][dst0 + 4096]);
    }
    __builtin_amdgcn_s_barrier();
    __builtin_amdgcn_sched_barrier(0);
    __builtin_amdgcn_s_setprio(1);
#pragma unroll
    for (int i = 0; i < 4; ++i)
#pragma unroll
      for (int j = 0; j < 4; ++j)
        acc[4 + i][j] = __builtin_amdgcn_mfma_f32_16x16x32_bf16(af[i], bfr[j], acc[4 + i][j], 0, 0, 0);
    __builtin_amdgcn_s_setprio(0);
    if (pre)               asm volatile("s_waitcnt vmcnt(8)" ::: "memory");
    else if ((s + 2) < NT) asm volatile("s_waitcnt vmcnt(4)" ::: "memory");
    else if ((s + 1) < NT) asm volatile("s_waitcnt vmcnt(0)" ::: "memory");
    __builtin_amdgcn_s_barrier();
    __builtin_amdgcn_sched_barrier(0);
  }

#pragma unroll
  for (int mi = 0; mi < 8; ++mi) {
    const int m = m0 + wm * 128 + mi * 16 + hi * 4;
#pragma unroll
    for (int j = 0; j < 4; ++j) {
      const int n = n0 + wn * 64 + j * 16 + r16;
#pragma unroll
      for (int q = 0; q < 4; ++q) {
        size_t idx = (size_t)(m + q) * N + n;
        float v = acc[mi][j][q];
        if constexpr (EP == EP_F32) {
          ((float*)Cp)[idx] = v;
        } else if constexpr (EP == EP_F32_BIAS) {
          ((float*)Cp)[idx] = v + bias[n];
        } else if constexpr (EP == EP_BF16) {
          ((bf16*)Cp)[idx] = (bf16)v;
        } else if constexpr (EP == EP_BF16_BIAS) {
          ((bf16*)Cp)[idx] = (bf16)(v + bias[n]);
        } else {
          float sg = v / (1.0f + __expf(-v));
          ((bf16*)Cp)[idx] = (bf16)(sg * (float)aux[idx]);
        }
      }
    }
  }
}

// ---------------- GEMM A-FF: fused dual-B (Wu,Wg) 256x128, silu epilogue ----------------

__global__ __launch_bounds__(512, 1) void gemm8ff(
    const bf16* __restrict__ A, const bf16* __restrict__ Bu, const bf16* __restrict__ Bg,
    bf16* __restrict__ Cp, int M, int N, int K) {
  __shared__ bf16 SA[4][256 * 32];   // 64 KiB
  __shared__ bf16 SU[4][128 * 32];   // 32 KiB
  __shared__ bf16 SG[4][128 * 32];   // 32 KiB

  const int tid = threadIdx.x;
  const int lane = tid & 63;
  const int r16 = lane & 15, hi = lane >> 4;
  const int wave = tid >> 6;
  const int wm = wave >> 2, wn = wave & 3;

  const int nwg = gridDim.x;
  const int orig = blockIdx.x;
  const int qq = nwg >> 3, rr = nwg & 7;
  const int xcd = orig & 7, cidx = orig >> 3;
  const int wg = (xcd < rr ? xcd * (qq + 1) : rr * (qq + 1) + (xcd - rr) * qq) + cidx;
  const int gM = M / 256;
  const int m0 = (wg % gM) * 256;
  const int n0 = (wg / gM) * 128;

  const int srow = tid >> 2;               // 0..127
  const int ccol = tid & 3;
  const int skey = (srow >> 1) & 3;
  const int gcol = (ccol ^ skey) * 8;
  const bf16* aS = A + (size_t)(m0 + srow) * K + gcol;
  const bf16* uS = Bu + (size_t)(n0 + srow) * K + gcol;
  const bf16* gSp = Bg + (size_t)(n0 + srow) * K + gcol;
  const int dst0 = tid * 8;

  const int rkey = (r16 >> 1) & 3;
  const int rchunk = (hi ^ rkey) * 8;

  f32x4 accU[8][2] = {}, accG[8][2] = {};
  const int NT = K / 32;

#pragma unroll
  for (int s = 0; s < 3; ++s) {
    gld16(aS + s * 32, &SA[s][dst0]);
    gld16(aS + s * 32 + (size_t)128 * K, &SA[s][dst0 + 4096]);
    gld16(uS + s * 32, &SU[s][dst0]);
    gld16(gSp + s * 32, &SG[s][dst0]);
  }
  asm volatile("s_waitcnt vmcnt(8)" ::: "memory");
  __builtin_amdgcn_s_barrier();
  __builtin_amdgcn_sched_barrier(0);

  for (int s = 0; s < NT; ++s) {
    const int cs = s & 3, ps = (s + 3) & 3;
    const bool pre = (s + 3) < NT;
    const size_t koff = (size_t)(s + 3) * 32;
    bf16x8 af[4], bu[2], bg[2];

#pragma unroll
    for (int j = 0; j < 2; ++j) {
      bu[j] = *(const bf16x8*)&SU[cs][(wn * 32 + j * 16 + r16) * 32 + rchunk];
      bg[j] = *(const bf16x8*)&SG[cs][(wn * 32 + j * 16 + r16) * 32 + rchunk];
    }
#pragma unroll
    for (int i = 0; i < 4; ++i)
      af[i] = *(const bf16x8*)&SA[cs][(wm * 128 + i * 16 + r16) * 32 + rchunk];
    if (pre) {
      gld16(aS + koff, &SA[ps][dst0]);
      gld16(aS + koff + (size_t)128 * K, &SA[ps][dst0 + 4096]);
    }
    __builtin_amdgcn_s_barrier();
    __builtin_amdgcn_sched_barrier(0);
    __builtin_amdgcn_s_setprio(1);
#pragma unroll
    for (int i = 0; i < 4; ++i)
#pragma unroll
      for (int j = 0; j < 2; ++j) {
        accU[i][j] = __builtin_amdgcn_mfma_f32_16x16x32_bf16(af[i], bu[j], accU[i][j], 0, 0, 0);
        accG[i][j] = __builtin_amdgcn_mfma_f32_16x16x32_bf16(af[i], bg[j], accG[i][j], 0, 0, 0);
      }
    __builtin_amdgcn_s_setprio(0);
    __builtin_amdgcn_s_barrier();
    __builtin_amdgcn_sched_barrier(0);

#pragma unroll
    for (int i = 0; i < 4; ++i)
      af[i] = *(const bf16x8*)&SA[cs][(wm * 128 + 64 + i * 16 + r16) * 32 + rchunk];
    if (pre) {
      gld16(uS + koff, &SU[ps][dst0]);
      gld16(gSp + koff, &SG[ps][dst0]);
    }
    __builtin_amdgcn_s_barrier();
    __builtin_amdgcn_sched_barrier(0);
    __builtin_amdgcn_s_setprio(1);
#pragma unroll
    for (int i = 0; i < 4; ++i)
#pragma unroll
      for (int j = 0; j < 2; ++j) {
        accU[4 + i][j] = __builtin_amdgcn_mfma_f32_16x16x32_bf16(af[i], bu[j], accU[4 + i][j], 0, 0, 0);
        accG[4 + i][j] = __builtin_amdgcn_mfma_f32_16x16x32_bf16(af[i], bg[j], accG[4 + i][j], 0, 0, 0);
      }
    __builtin_amdgcn_s_setprio(0);
    if (pre)               asm volatile("s_waitcnt vmcnt(8)" ::: "memory");
    else if ((s + 2) < NT) asm volatile("s_waitcnt vmcnt(4)" ::: "memory");
    else if ((s + 1) < NT) asm volatile("s_waitcnt vmcnt(0)" ::: "memory");
    __builtin_amdgcn_s_barrier();
    __builtin_amdgcn_sched_barrier(0);
  }

#pragma unroll
  for (int mi = 0; mi < 8; ++mi) {
    const int m = m0 + wm * 128 + mi * 16 + hi * 4;
#pragma unroll
    for (int j = 0; j < 2; ++j) {
      const int n = n0 + wn * 32 + j * 16 + r16;
#pragma unroll
      for (int q = 0; q < 4; ++q) {
        float u = accU[mi][j][q];
        float g = accG[mi][j][q];
        float sg = g / (1.0f + __expf(-g));
        Cp[(size_t)(m + q) * N + n] = (bf16)(sg * u);
      }
    }
  }
}

// ---------------- GEMM B: BMxBN ring (generalized; LA/LB staging passes) ----------------

template <int BM, int BN, int WMW, int WNW, int EP>
__global__ __launch_bounds__(WMW * WNW * 64, 2) void gemmk(
    const bf16* __restrict__ A, const bf16* __restrict__ Bt, void* __restrict__ Cp,
    const float* __restrict__ bias, const bf16* __restrict__ aux,
    int M, int N, int K) {
  constexpr int BK = 32;
  constexpr int MF = BM / (WMW * 16);
  constexpr int NF = BN / (WNW * 16);
  constexpr int LA = BM / 64;
  constexpr int LB = BN / 64;
  constexpr int VM_MAIN = 2 * LA + LB;
  constexpr int VM_TAIL = LA + LB;
  __shared__ bf16 sA[4][BM * BK];
  __shared__ bf16 sB[4][BN * BK];

  const int tid = threadIdx.x;
  const int lane = tid & 63;
  const int r16 = lane & 15, hi = lane >> 4;
  const int wave = tid >> 6;
  const int wm = wave / WNW, wn = wave % WNW;

  const int nwg = gridDim.x;
  const int orig = blockIdx.x;
  const int qq = nwg >> 3, rr = nwg & 7;
  const int xcd = orig & 7, cidx = orig >> 3;
  const int wg = (xcd < rr ? xcd * (qq + 1) : rr * (qq + 1) + (xcd - rr) * qq) + cidx;
  const int gM = M / BM;
  const int m0 = (wg % gM) * BM;
  const int n0 = (wg / gM) * BN;

  const int srow = tid >> 2;
  const int ccol = tid & 3;
  const int skey = (srow >> 1) & 3;
  const int gcol = ((ccol ^ skey)) * 8;
  const bf16* aS = A + (size_t)(m0 + srow) * K + gcol;
  const bf16* bS = Bt + (size_t)(n0 + srow) * K + gcol;
  const int dst0 = srow * BK + ccol * 8;

  const int rkey = (r16 >> 1) & 3;
  const int rchunk = (hi ^ rkey) * 8;

  f32x4 acc[MF][NF] = {};
  const int NT = K / BK;

#pragma unroll
  for (int t0_ = 0; t0_ < 2; ++t0_) {
#pragma unroll
    for (int p = 0; p < LA; ++p)
      gld16(aS + t0_ * BK + (size_t)p * 64 * K, &sA[t0_][dst0 + p * 64 * BK]);
#pragma unroll
    for (int p = 0; p < LB; ++p)
      gld16(bS + t0_ * BK + (size_t)p * 64 * K, &sB[t0_][dst0 + p * 64 * BK]);
  }

  for (int t = 0; t < NT; ++t) {
    const int cb = t & 3;
    const int pb = (t + 2) & 3;
    const bool pre = (t + 2) < NT;
    if (pre) {
#pragma unroll
      for (int p = 0; p < LA; ++p)
        gld16(aS + (size_t)(t + 2) * BK + (size_t)p * 64 * K, &sA[pb][dst0 + p * 64 * BK]);
    }
    if (pre)             asm volatile("s_waitcnt vmcnt(%0)" :: "i"(VM_MAIN) : "memory");
    else if (t + 1 < NT) asm volatile("s_waitcnt vmcnt(%0)" :: "i"(VM_TAIL) : "memory");
    else                 asm volatile("s_waitcnt vmcnt(0)" ::: "memory");
    __builtin_amdgcn_s_barrier();
    __builtin_amdgcn_sched_barrier(0);

    bf16x8 bf_[NF];
#pragma unroll
    for (int j = 0; j < NF; ++j)
      bf_[j] = *(const bf16x8*)&sB[cb][(wn * (NF * 16) + j * 16 + r16) * BK + rchunk];
    if (pre) {
#pragma unroll
      for (int p = 0; p < LB; ++p)
        gld16(bS + (size_t)(t + 2) * BK + (size_t)p * 64 * K, &sB[pb][dst0 + p * 64 * BK]);
    }
    bf16x8 af[MF];
#pragma unroll
    for (int i = 0; i < MF; ++i)
      af[i] = *(const bf16x8*)&sA[cb][(wm * (MF * 16) + i * 16 + r16) * BK + rchunk];
    __builtin_amdgcn_s_setprio(1);
#pragma unroll
    for (int i = 0; i < MF; ++i)
#pragma unroll
      for (int j = 0; j < NF; ++j)
        acc[i][j] = __builtin_amdgcn_mfma_f32_16x16x32_bf16(af[i], bf_[j], acc[i][j], 0, 0, 0);
    __builtin_amdgcn_s_setprio(0);
  }

#pragma unroll
  for (int i = 0; i < MF; ++i) {
    const int m = m0 + wm * (MF * 16) + i * 16 + hi * 4;
#pragma unroll
    for (int j = 0; j < NF; ++j) {
      const int n = n0 + wn * (NF * 16) + j * 16 + r16;
#pragma unroll
      for (int q = 0; q < 4; ++q) {
        size_t idx = (size_t)(m + q) * N + n;
        float v = acc[i][j][q];
        if constexpr (EP == EP_F32) {
          ((float*)Cp)[idx] = v;
        } else if constexpr (EP == EP_F32_BIAS) {
          ((float*)Cp)[idx] = v + bias[n];
        } else if constexpr (EP == EP_BF16) {
          ((bf16*)Cp)[idx] = (bf16)v;
        } else if constexpr (EP == EP_BF16_BIAS) {
          ((bf16*)Cp)[idx] = (bf16)(v + bias[n]);
        } else {
          float sg = v / (1.0f + __expf(-v));
          ((bf16*)Cp)[idx] = (bf16)(sg * (float)aux[idx]);
        }
      }
    }
  }
}

// ---------------- flash attention: swapped QK^T, QBLK=128 (2 Q-frags/wave) ----------------

__global__ __launch_bounds__(256, 2) void attn_flash(
    const bf16* __restrict__ Qp, const bf16* __restrict__ Kp, int ldk,
    const bf16* __restrict__ Vt, bf16* __restrict__ Op) {
  __shared__ bf16 Ks[2][128 * 32];
  __shared__ bf16 Vs[4][64 * 32];
  __shared__ bf16 Ps[4][2][16 * 144];
  const int tid = threadIdx.x, lane = tid & 63, wave = tid >> 6;
  const int h = blockIdx.y, b = blockIdx.z;
  const int r16 = lane & 15, hi = lane >> 4;
  const int qbase = blockIdx.x * 128 + wave * 32;

  const float QS = 0.1803368801f;          // 0.125 * log2(e)
  bf16x8 qa[2][2];
#pragma unroll
  for (int f = 0; f < 2; ++f) {
    const bf16* qp = Qp + (size_t)(b * TT + qbase + f * 16 + r16) * ldk + h * DH + hi * 8;
    bf16x8 q0 = *(const bf16x8*)qp;
    bf16x8 q1 = *(const bf16x8*)(qp + 32);
#pragma unroll
    for (int e = 0; e < 8; ++e) {
      qa[f][0][e] = (bf16)((float)q0[e] * QS);
      qa[f][1][e] = (bf16)((float)q1[e] * QS);
    }
  }
  const bf16* kBase = Kp + (size_t)(b * TT) * ldk + h * DH;
  const bf16* vBase = Vt + (size_t)(b * NH + h) * DH * TT;

  const int srow = tid >> 2, ccol = tid & 3;
  const int skey = (srow >> 1) & 3;
  const int scolS = (ccol ^ skey) * 8;
  const int dstc = ccol * 8;
  const int rkey = (r16 >> 1) & 3;
  const int rchunk = (hi ^ rkey) * 8;

  float m_run[2] = {-1e30f, -1e30f};
  float l_run[2] = {0.f, 0.f};
  f32x4 oacc[2][4] = {};

  for (int kt = 0; kt < TT; kt += 128) {
#pragma unroll
    for (int half = 0; half < 2; ++half) {
      gld16(kBase + (size_t)(kt + srow) * ldk + half * 32 + scolS, &Ks[half][srow * 32 + dstc]);
      gld16(kBase + (size_t)(kt + 64 + srow) * ldk + half * 32 + scolS, &Ks[half][(64 + srow) * 32 + dstc]);
    }
#pragma unroll
    for (int ks = 0; ks < 4; ++ks)
      gld16(vBase + (size_t)srow * TT + kt + ks * 32 + scolS, &Vs[ks][srow * 32 + dstc]);
    __syncthreads();

#pragma unroll
    for (int f = 0; f < 2; ++f) {
      f32x4 s[8];
      __builtin_amdgcn_s_setprio(1);
#pragma unroll
      for (int kg = 0; kg < 8; ++kg) {
        f32x4 z = {};
        bf16x8 kb0 = *(const bf16x8*)&Ks[0][(kg * 16 + r16) * 32 + rchunk];
        bf16x8 kb1 = *(const bf16x8*)&Ks[1][(kg * 16 + r16) * 32 + rchunk];
        z = __builtin_amdgcn_mfma_f32_16x16x32_bf16(kb0, qa[f][0], z, 0, 0, 0);
        z = __builtin_amdgcn_mfma_f32_16x16x32_bf16(kb1, qa[f][1], z, 0, 0, 0);
        s[kg] = z;
      }
      __builtin_amdgcn_s_setprio(0);

      float pm = s[0][0];
#pragma unroll
      for (int kg = 0; kg < 8; ++kg)
#pragma unroll
        for (int i = 0; i < 4; ++i) pm = fmaxf(pm, s[kg][i]);
      pm = fmaxf(pm, __shfl_xor(pm, 16));
      pm = fmaxf(pm, __shfl_xor(pm, 32));

      if (!__all(pm - m_run[f] <= 11.5411f)) {
        float mnew = fmaxf(m_run[f], pm);
        float fr = exp2f(m_run[f] - mnew);
        m_run[f] = mnew;
        l_run[f] *= fr;
#pragma unroll
        for (int i = 0; i < 4; ++i) {
          float fi = __shfl(fr, hi * 4 + i);
#pragma unroll
          for (int n = 0; n < 4; ++n) oacc[f][n][i] *= fi;
        }
      }

      float lsum = 0.f;
#pragma unroll
      for (int kg = 0; kg < 8; ++kg) {
        float p0 = exp2f(s[kg][0] - m_run[f]);
        float p1 = exp2f(s[kg][1] - m_run[f]);
        float p2 = exp2f(s[kg][2] - m_run[f]);
        float p3 = exp2f(s[kg][3] - m_run[f]);
        lsum += (p0 + p1) + (p2 + p3);
        bf16x4 pk = {(bf16)p0, (bf16)p1, (bf16)p2, (bf16)p3};
        *(bf16x4*)&Ps[wave][f][r16 * 144 + kg * 16 + hi * 4] = pk;
      }
      l_run[f] += lsum;

      __builtin_amdgcn_s_setprio(1);
#pragma unroll
      for (int ks = 0; ks < 4; ++ks) {
        bf16x8 pa = *(const bf16x8*)&Ps[wave][f][r16 * 144 + ks * 32 + hi * 8];
#pragma unroll
        for (int n = 0; n < 4; ++n) {
          bf16x8 vb = *(const bf16x8*)&Vs[ks][(n * 16 + r16) * 32 + rchunk];
          oacc[f][n] = __builtin_amdgcn_mfma_f32_16x16x32_bf16(pa, vb, oacc[f][n], 0, 0, 0);
        }
      }
      __builtin_amdgcn_s_setprio(0);
    }
    __syncthreads();
  }

#pragma unroll
  for (int f = 0; f < 2; ++f) {
    float lq = l_run[f];
    lq += __shfl_xor(lq, 16);
    lq += __shfl_xor(lq, 32);
    float invq = 1.0f / lq;
#pragma unroll
    for (int i = 0; i < 4; ++i) {
      float inv_i = __shfl(invq, hi * 4 + i);
      int trow = qbase + f * 16 + hi * 4 + i;
      size_t base = ((size_t)b * TT + trow) * DIM + h * DH;
#pragma unroll
      for (int n = 0; n < 4; ++n)
        Op[base + n * 16 + r16] = (bf16)(oacc[f][n][i] * inv_i);
    }
  }
}

// ---------------- residual + rmsnorm ----------------

__global__ __launch_bounds__(256) void resid_rms(
    const float* __restrict__ xin, const float* __restrict__ y, const float* __restrict__ wgt,
    float* __restrict__ xf_out, bf16* __restrict__ xb_out) {
  __shared__ float red[4];
  const int r = blockIdx.x, tid = threadIdx.x;
  const size_t base = (size_t)r * DIM + tid * 4;
  float4 v = *(const float4*)(xin + base);
  float4 u = *(const float4*)(y + base);
  v.x += u.x; v.y += u.y; v.z += u.z; v.w += u.w;
  float ss = v.x * v.x + v.y * v.y + v.z * v.z + v.w * v.w;
#pragma unroll
  for (int d = 1; d < 64; d <<= 1) ss += __shfl_xor(ss, d);
  if ((tid & 63) == 0) red[tid >> 6] = ss;
  __syncthreads();
  ss = red[0] + red[1] + red[2] + red[3];
  float sc = rsqrtf(ss * (1.0f / DIM) + 1e-8f);
  const float4 wv = *(const float4*)(wgt + tid * 4);
  float o0 = v.x * sc * wv.x, o1 = v.y * sc * wv.y, o2 = v.z * sc * wv.z, o3 = v.w * sc * wv.w;
  if (xf_out) {
    float4 ov = {o0, o1, o2, o3};
    *(float4*)(xf_out + base) = ov;
  }
  bf16x4 ob = {(bf16)o0, (bf16)o1, (bf16)o2, (bf16)o3};
  *(bf16x4*)(xb_out + base) = ob;
}

// ---------------- slot softmax rows (scale D^-0.5 = 1/32) ----------------

__global__ __launch_bounds__(256) void softmax_rows(const float* __restrict__ Sc, bf16* __restrict__ P) {
  __shared__ float red[4];
  const int r = blockIdx.x, tid = threadIdx.x;
  const float* row = Sc + (size_t)r * NSLOT;
  float4 v[4];
#pragma unroll
  for (int i = 0; i < 4; ++i) v[i] = *(const float4*)(row + tid * 4 + i * 1024);
  float mx = -1e30f;
#pragma unroll
  for (int i = 0; i < 4; ++i)
    mx = fmaxf(fmaxf(fmaxf(fmaxf(mx, v[i].x), v[i].y), v[i].z), v[i].w);
#pragma unroll
  for (int d = 1; d < 64; d <<= 1) mx = fmaxf(mx, __shfl_xor(mx, d));
  if ((tid & 63) == 0) red[tid >> 6] = mx;
  __syncthreads();
  mx = fmaxf(fmaxf(red[0], red[1]), fmaxf(red[2], red[3]));
  __syncthreads();
  float e[16];
  float sum = 0.f;
#pragma unroll
  for (int i = 0; i < 4; ++i) {
    e[i * 4 + 0] = __expf((v[i].x - mx) * 0.03125f);
    e[i * 4 + 1] = __expf((v[i].y - mx) * 0.03125f);
    e[i * 4 + 2] = __expf((v[i].z - mx) * 0.03125f);
    e[i * 4 + 3] = __expf((v[i].w - mx) * 0.03125f);
    sum += e[i * 4 + 0] + e[i * 4 + 1] + e[i * 4 + 2] + e[i * 4 + 3];
  }
#pragma unroll
  for (int d = 1; d < 64; d <<= 1) sum += __shfl_xor(sum, d);
  if ((tid & 63) == 0) red[tid >> 6] = sum;
  __syncthreads();
  sum = red[0] + red[1] + red[2] + red[3];
  float inv = 1.0f / sum;
#pragma unroll
  for (int i = 0; i < 4; ++i) {
    bf16x4 ob = {(bf16)(e[i * 4 + 0] * inv), (bf16)(e[i * 4 + 1] * inv),
                 (bf16)(e[i * 4 + 2] * inv), (bf16)(e[i * 4 + 3] * inv)};
    *(bf16x4*)(P + (size_t)r * NSLOT + tid * 4 + i * 1024) = ob;
  }
}

// ---------------- host orchestration ----------------

extern "C" void kernel_launch(void* const* d_in, const int* in_sizes, int n_in,
                              void* d_out, int out_size, void* d_ws, size_t ws_size,
                              hipStream_t stream) {
  (void)in_sizes; (void)n_in; (void)out_size;
  const int* ids = (const int*)d_in[0];
  const float* emb = (const float*)d_in[1];
  const float* Wq = (const float*)d_in[2];
  const float* Wk = (const float*)d_in[3];
  const float* Wv = (const float*)d_in[4];
  const float* Wo = (const float*)d_in[5];
  const float* bo = (const float*)d_in[6];
  const float* n1 = (const float*)d_in[7];
  const float* Wg = (const float*)d_in[8];
  const float* Wu = (const float*)d_in[9];
  const float* Wd = (const float*)d_in[10];
  const float* n2 = (const float*)d_in[11];
  const float* memp = (const float*)d_in[12];
  const float* Wsp = (const float*)d_in[13];
  const float* bsp = (const float*)d_in[14];
  const float* Wrp = (const float*)d_in[15];
  const float* brp = (const float*)d_in[16];
  const float* nout = (const float*)d_in[17];

  char* w = (char*)d_ws;
  auto alloc = [&](size_t bytes) -> void* {
    void* p = (void*)w;
    w += (bytes + 255) & ~(size_t)255;
    return p;
  };

  const size_t dd = (size_t)DIM * DIM;
  const size_t dff = (size_t)DIM * FFD;

  bf16* tok_b = (bf16*)alloc((size_t)NV * DIM * 2);
  bf16* mem_b = (bf16*)alloc((size_t)NSLOT * DIM * 2);
  bf16* memT  = (bf16*)alloc((size_t)NSLOT * DIM * 2);
  bf16* WspT  = (bf16*)alloc(dd * 2);
  bf16* WrpT  = (bf16*)alloc(dd * 2);
  float* xf   = (float*)alloc((size_t)BT * DIM * 4);
  bf16* xb    = (bf16*)alloc((size_t)BT * DIM * 2);
  float* yb   = (float*)alloc((size_t)BT * DIM * 4);
  bf16* W3T   = (bf16*)alloc(3 * dd * 2);   // [WqT | WkT | WvT] rows
  bf16* WoT   = (bf16*)alloc(dd * 2);
  bf16* WgT   = (bf16*)alloc(dff * 2);
  bf16* WuT   = (bf16*)alloc(dff * 2);
  bf16* WdT   = (bf16*)alloc(dff * 2);
  bf16* qkv   = (bf16*)alloc((size_t)BT * 3 * DIM * 2);
  bf16* vT_   = (bf16*)alloc((size_t)BT * DIM * 2);
  bf16* ot_   = (bf16*)alloc((size_t)BT * DIM * 2);
  bf16* qb    = (bf16*)alloc((size_t)BT * DIM * 2);
  bf16* rb    = (bf16*)alloc((size_t)BT * DIM * 2);
  bf16* hb    = (bf16*)alloc((size_t)BT * DIM * 2);

  size_t used = (size_t)(w - (char*)d_ws);
  size_t region_bytes = (size_t)BT * NSLOT * 4 + (size_t)BT * NSLOT * 2;
  char* region;
  if (used + region_bytes <= ws_size) region = (char*)alloc(region_bytes);
  else region = (char*)d_out;
  bf16* Hb = (bf16*)region;
  float* scoresF = (float*)region;
  bf16* attnb = (bf16*)(region + (size_t)BT * NSLOT * 4);

  dim3 blkT(8, 32);
  dim3 blkV(32, 8);

  cvt_bf16<<<NV * DIM / 1024, 256, 0, stream>>>(emb, tok_b, (long)NV * DIM);
  cvt_bf16<<<NSLOT * DIM / 1024, 256, 0, stream>>>(memp, mem_b, (long)NSLOT * DIM);
  {
    TBatch tb{};
    tb.src[0] = memp; tb.dst[0] = memT; tb.R[0] = NSLOT; tb.C[0] = DIM; tb.base[0] = 0;
    tb.src[1] = Wsp;  tb.dst[1] = WspT; tb.R[1] = DIM;   tb.C[1] = DIM; tb.base[1] = 4096;
    tb.src[2] = Wrp;  tb.dst[2] = WrpT; tb.R[2] = DIM;   tb.C[2] = DIM; tb.base[2] = 5120;
    for (int i = 3; i < 7; ++i) { tb.base[i] = 0x7fffffff; tb.src[i] = memp; tb.dst[i] = memT; tb.R[i] = 32; tb.C[i] = 32; }
    transpose_cvt_batch<<<6144, blkT, 0, stream>>>(tb);
  }
  embed_rope<<<BT, 256, 0, stream>>>(ids, emb, xf, xb);

  for (int l = 0; l < NL; ++l) {
    {
      TBatch tb{};
      tb.src[0] = Wq + l * dd;  tb.dst[0] = W3T;          tb.R[0] = DIM; tb.C[0] = DIM;  tb.base[0] = 0;
      tb.src[1] = Wk + l * dd;  tb.dst[1] = W3T + dd;     tb.R[1] = DIM; tb.C[1] = DIM;  tb.base[1] = 1024;
      tb.src[2] = Wv + l * dd;  tb.dst[2] = W3T + 2 * dd; tb.R[2] = DIM; tb.C[2] = DIM;  tb.base[2] = 2048;
      tb.src[3] = Wo + l * dd;  tb.dst[3] = WoT;          tb.R[3] = DIM; tb.C[3] = DIM;  tb.base[3] = 3072;
      tb.src[4] = Wg + l * dff; tb.dst[4] = WgT;          tb.R[4] = DIM; tb.C[4] = FFD;  tb.base[4] = 4096;
      tb.src[5] = Wu + l * dff; tb.dst[5] = WuT;          tb.R[5] = DIM; tb.C[5] = FFD;  tb.base[5] = 8192;
      tb.src[6] = Wd + l * dff; tb.dst[6] = WdT;          tb.R[6] = FFD; tb.C[6] = DIM;  tb.base[6] = 12288;
      transpose_cvt_batch<<<16384, blkT, 0, stream>>>(tb);
    }

    gemm8<EP_BF16><<<dim3(16 * 12), 512, 0, stream>>>(
        xb, W3T, qkv, nullptr, nullptr, BT, 3 * DIM, DIM);
    transpose_v<<<dim3(TT / 32, DH / 32, BB * NH), blkV, 0, stream>>>(qkv + 2 * DIM, 3 * DIM, vT_);
    attn_flash<<<dim3(TT / 128, NH, BB), 256, 0, stream>>>(qkv, qkv + DIM, 3 * DIM, vT_, ot_);
    gemmk<128, 64, 2, 2, EP_F32_BIAS><<<dim3(32 * 16), 256, 0, stream>>>(
        ot_, WoT, yb, bo + l * DIM, nullptr, BT, DIM, DIM);
    resid_rms<<<BT, 256, 0, stream>>>(xf, yb, n1 + l * DIM, xf, xb);
    gemm8ff<<<dim3(16 * 32), 512, 0, stream>>>(
        xb, WuT, WgT, Hb, BT, FFD, DIM);
    gemmk<128, 64, 2, 2, EP_F32><<<dim3(32 * 16), 256, 0, stream>>>(
        Hb, WdT, yb, nullptr, nullptr, BT, DIM, FFD);
    resid_rms<<<BT, 256, 0, stream>>>(xf, yb, n2 + l * DIM, xf, xb);
  }

  gemmk<128, 64, 2, 2, EP_BF16_BIAS><<<dim3(32 * 16), 256, 0, stream>>>(
      xb, WspT, qb, bsp, nullptr, BT, DIM, DIM);
  gemm8<EP_F32><<<dim3(16 * 16), 512, 0, stream>>>(
      qb, mem_b, scoresF, nullptr, nullptr, BT, NSLOT, DIM);
  softmax_rows<<<BT, 256, 0, stream>>>(scoresF, attnb);
  gemmk<128, 64, 2, 2, EP_BF16><<<dim3(32 * 16), 256, 0, stream>>>(
      attnb, memT, rb, nullptr, nullptr, BT, DIM, NSLOT);
  gemmk<128, 64, 2, 2, EP_F32_BIAS><<<dim3(32 * 16), 256, 0, stream>>>(
      rb, WrpT, yb, brp, nullptr, BT, DIM, DIM);
  resid_rms<<<BT, 256, 0, stream>>>(xf, yb, nout, nullptr, hb);
  gemm8<EP_F32><<<dim3(16 * 125), 512, 0, stream>>>(
      hb, tok_b, (float*)d_out, nullptr, nullptr, BT, NV, DIM);
}

// Round 15
// 2600.128 us; speedup vs baseline: 1.0756x; 1.0147x over previous
//
#include <hip/hip_runtime.h>

typedef __bf16 bf16;
typedef __attribute__((ext_vector_type(8))) __bf16 bf16x8;
typedef __attribute__((ext_vector_type(4))) __bf16 bf16x4;
typedef __attribute__((ext_vector_type(4))) float f32x4;

#define NL 6
#define DIM 1024
#define NH 16
#define DH 64
#define TT 2048
#define BB 2
#define BT 4096
#define FFD 4096
#define NSLOT 4096
#define NV 32000

__device__ __forceinline__ void gld16(const void* g, void* l) {
  __builtin_amdgcn_global_load_lds(
      (const __attribute__((address_space(1))) void*)g,
      (__attribute__((address_space(3))) void*)l, 16, 0, 0);
}

// ---------------- conversion / transpose kernels ----------------

__global__ void cvt_bf16(const float* __restrict__ s, bf16* __restrict__ d, long n) {
  long i = ((long)blockIdx.x * 256 + threadIdx.x) * 4;
  if (i + 3 < n) {
    float4 v = *(const float4*)(s + i);
    bf16x4 o = {(bf16)v.x, (bf16)v.y, (bf16)v.z, (bf16)v.w};
    *(bf16x4*)(d + i) = o;
  }
}

// Batched transpose: up to 7 segments in one launch (verified R12 body).
// NOTE (R13 lesson): keep per-layer (not hoisted) — the transpose doubles as
// an L3 prefetch of the layer's weights; hoisting all layers evicts and
// forces cold HBM weight reads (+163 us measured).
struct TBatch {
  const float* src[7];
  bf16* dst[7];
  int R[7], C[7];
  int base[7];
};

__global__ void transpose_cvt_batch(TBatch tb) {
  const int bid = blockIdx.x;
  int s = 0;
#pragma unroll
  for (int i = 1; i < 7; ++i)
    if (bid >= tb.base[i]) s = i;
  const int local = bid - tb.base[s];
  const int R = tb.R[s], C = tb.C[s];
  const float* __restrict__ src = tb.src[s];
  bf16* __restrict__ dst = tb.dst[s];
  const int tilesPerRow = C / 32;
  const int c0 = (local % tilesPerRow) * 32;
  const int r0 = (local / tilesPerRow) * 32;

  __shared__ float tile[32][33];
  int tx = threadIdx.x;  // 0..7
  int ty = threadIdx.y;  // 0..31
  float4 v = *(const float4*)(src + (size_t)(r0 + ty) * C + c0 + tx * 4);
  tile[ty][tx * 4 + 0] = v.x;
  tile[ty][tx * 4 + 1] = v.y;
  tile[ty][tx * 4 + 2] = v.z;
  tile[ty][tx * 4 + 3] = v.w;
  __syncthreads();
  bf16x4 o = {(bf16)tile[tx * 4 + 0][ty], (bf16)tile[tx * 4 + 1][ty],
              (bf16)tile[tx * 4 + 2][ty], (bf16)tile[tx * 4 + 3][ty]};
  *(bf16x4*)(dst + (size_t)(c0 + ty) * R + r0 + tx * 4) = o;
}

// v [b*T+t][ldv stride, h*DH+dh] bf16 -> vT [(b*NH+h)*DH+dh][t] bf16
__global__ void transpose_v(const bf16* __restrict__ v, int ldv, bf16* __restrict__ vT) {
  __shared__ bf16 tile[32][33];
  int t0 = blockIdx.x * 32, d0 = blockIdx.y * 32, bh = blockIdx.z;
  int b = bh >> 4, h = bh & 15;
  int tx = threadIdx.x, ty = threadIdx.y;
#pragma unroll
  for (int i = 0; i < 4; ++i)
    tile[ty + i * 8][tx] = v[(size_t)(b * TT + t0 + ty + i * 8) * ldv + h * DH + d0 + tx];
  __syncthreads();
#pragma unroll
  for (int i = 0; i < 4; ++i)
    vT[((size_t)bh * DH + d0 + ty + i * 8) * TT + t0 + tx] = tile[tx][ty + i * 8];
}

// ---------------- embedding + rope ----------------

__global__ void embed_rope(const int* __restrict__ ids, const float* __restrict__ emb,
                           float* __restrict__ xf, bf16* __restrict__ xb) {
  int bt = blockIdx.x;
  int t = bt & (TT - 1);
  int id = ids[bt];
  const float* row = emb + (size_t)id * DIM;
  for (int p = threadIdx.x; p < DIM / 2; p += 256) {
    float x1 = row[2 * p], x2 = row[2 * p + 1];
    float inv = __expf(-9.210340371976184f * (float)p * (1.0f / 512.0f));
    float ang = (float)t * inv;
    float c = cosf(ang), s = sinf(ang);
    float o1 = x1 * c - x2 * s;
    float o2 = x1 * s + x2 * c;
    size_t base = (size_t)bt * DIM + 2 * p;
    xf[base] = o1; xf[base + 1] = o2;
    xb[base] = (bf16)o1; xb[base + 1] = (bf16)o2;
  }
}

enum { EP_BF16 = 0, EP_F32 = 1, EP_F32_BIAS = 2, EP_BF16_BIAS = 3, EP_SILU_MUL = 4 };

// ---------------- GEMM A: 256x256, 4-slot half-K ring, 512 thr (frozen) ----------------

template <int EP>
__global__ __launch_bounds__(512, 1) void gemm8(
    const bf16* __restrict__ A, const bf16* __restrict__ Bt, void* __restrict__ Cp,
    const float* __restrict__ bias, const bf16* __restrict__ aux,
    int M, int N, int K) {
  __shared__ bf16 S[4][2][256 * 32];   // [slot][A=0/B=1][256 rows x 32] = 128 KiB

  const int tid = threadIdx.x;
  const int lane = tid & 63;
  const int r16 = lane & 15, hi = lane >> 4;
  const int wave = tid >> 6;
  const int wm = wave >> 2, wn = wave & 3;

  const int nwg = gridDim.x;
  const int orig = blockIdx.x;
  const int qq = nwg >> 3, rr = nwg & 7;
  const int xcd = orig & 7, cidx = orig >> 3;
  const int wg = (xcd < rr ? xcd * (qq + 1) : rr * (qq + 1) + (xcd - rr) * qq) + cidx;
  const int gM = M / 256;
  const int m0 = (wg % gM) * 256;
  const int n0 = (wg / gM) * 256;

  const int srow = tid >> 2;               // 0..127
  const int ccol = tid & 3;
  const int skey = (srow >> 1) & 3;
  const int gcol = (ccol ^ skey) * 8;      // pre-swizzled global col
  const bf16* aS = A + (size_t)(m0 + srow) * K + gcol;
  const bf16* bS = Bt + (size_t)(n0 + srow) * K + gcol;
  const int dst0 = tid * 8;                // linear LDS dest

  const int rkey = (r16 >> 1) & 3;
  const int rchunk = (hi ^ rkey) * 8;

  f32x4 acc[8][4] = {};
  const int NT = K / 32;

#pragma unroll
  for (int s = 0; s < 3; ++s) {
    gld16(aS + s * 32, &S[s][0][dst0]);
    gld16(aS + s * 32 + (size_t)128 * K, &S[s][0][dst0 + 4096]);
    gld16(bS + s * 32, &S[s][1][dst0]);
    gld16(bS + s * 32 + (size_t)128 * K, &S[s][1][dst0 + 4096]);
  }
  asm volatile("s_waitcnt vmcnt(8)" ::: "memory");
  __builtin_amdgcn_s_barrier();
  __builtin_amdgcn_sched_barrier(0);

  for (int s = 0; s < NT; ++s) {
    const int cs = s & 3, ps = (s + 3) & 3;
    const bool pre = (s + 3) < NT;
    const bf16* SA = S[cs][0];
    const bf16* SB = S[cs][1];
    const size_t koff = (size_t)(s + 3) * 32;
    bf16x8 af[4], bfr[4];

#pragma unroll
    for (int j = 0; j < 4; ++j)
      bfr[j] = *(const bf16x8*)&SB[(wn * 64 + j * 16 + r16) * 32 + rchunk];
#pragma unroll
    for (int i = 0; i < 4; ++i)
      af[i] = *(const bf16x8*)&SA[(wm * 128 + i * 16 + r16) * 32 + rchunk];
    if (pre) {
      gld16(aS + koff, &S[ps][0][dst0]);
      gld16(aS + koff + (size_t)128 * K, &S[ps][0][dst0 + 4096]);
    }
    __builtin_amdgcn_s_barrier();
    __builtin_amdgcn_sched_barrier(0);
    __builtin_amdgcn_s_setprio(1);
#pragma unroll
    for (int i = 0; i < 4; ++i)
#pragma unroll
      for (int j = 0; j < 4; ++j)
        acc[i][j] = __builtin_amdgcn_mfma_f32_16x16x32_bf16(af[i], bfr[j], acc[i][j], 0, 0, 0);
    __builtin_amdgcn_s_setprio(0);
    __builtin_amdgcn_s_barrier();
    __builtin_amdgcn_sched_barrier(0);

#pragma unroll
    for (int i = 0; i < 4; ++i)
      af[i] = *(const bf16x8*)&SA[(wm * 128 + 64 + i * 16 + r16) * 32 + rchunk];
    if (pre) {
      gld16(bS + koff, &S[ps][1][dst0]);
      gld16(bS + koff + (size_t)128 * K, &S[ps][1][dst0 + 4096]);
    }
    __builtin_amdgcn_s_barrier();
    __builtin_amdgcn_sched_barrier(0);
    __builtin_amdgcn_s_setprio(1);
#pragma unroll
    for (int i = 0; i < 4; ++i)
#pragma unroll
      for (int j = 0; j < 4; ++j)
        acc[4 + i][j] = __builtin_amdgcn_mfma_f32_16x16x32_bf16(af[i], bfr[j], acc[4 + i][j], 0, 0, 0);
    __builtin_amdgcn_s_setprio(0);
    if (pre)               asm volatile("s_waitcnt vmcnt(8)" ::: "memory");
    else if ((s + 2) < NT) asm volatile("s_waitcnt vmcnt(4)" ::: "memory");
    else if ((s + 1) < NT) asm volatile("s_waitcnt vmcnt(0)" ::: "memory");
    __builtin_amdgcn_s_barrier();
    __builtin_amdgcn_sched_barrier(0);
  }

#pragma unroll
  for (int mi = 0; mi < 8; ++mi) {
    const int m = m0 + wm * 128 + mi * 16 + hi * 4;
#pragma unroll
    for (int j = 0; j < 4; ++j) {
      const int n = n0 + wn * 64 + j * 16 + r16;
#pragma unroll
      for (int q = 0; q < 4; ++q) {
        size_t idx = (size_t)(m + q) * N + n;
        float v = acc[mi][j][q];
        if constexpr (EP == EP_F32) {
          ((float*)Cp)[idx] = v;
        } else if constexpr (EP == EP_F32_BIAS) {
          ((float*)Cp)[idx] = v + bias[n];
        } else if constexpr (EP == EP_BF16) {
          ((bf16*)Cp)[idx] = (bf16)v;
        } else if constexpr (EP == EP_BF16_BIAS) {
          ((bf16*)Cp)[idx] = (bf16)(v + bias[n]);
        } else {
          float sg = v / (1.0f + __expf(-v));
          ((bf16*)Cp)[idx] = (bf16)(sg * (float)aux[idx]);
        }
      }
    }
  }
}

// ---------------- GEMM A-FF: fused dual-B (Wu,Wg) 256x128, silu epilogue ----------------

__global__ __launch_bounds__(512, 1) void gemm8ff(
    const bf16* __restrict__ A, const bf16* __restrict__ Bu, const bf16* __restrict__ Bg,
    bf16* __restrict__ Cp, int M, int N, int K) {
  __shared__ bf16 SA[4][256 * 32];   // 64 KiB
  __shared__ bf16 SU[4][128 * 32];   // 32 KiB
  __shared__ bf16 SG[4][128 * 32];   // 32 KiB

  const int tid = threadIdx.x;
  const int lane = tid & 63;
  const int r16 = lane & 15, hi = lane >> 4;
  const int wave = tid >> 6;
  const int wm = wave >> 2, wn = wave & 3;

  const int nwg = gridDim.x;
  const int orig = blockIdx.x;
  const int qq = nwg >> 3, rr = nwg & 7;
  const int xcd = orig & 7, cidx = orig >> 3;
  const int wg = (xcd < rr ? xcd * (qq + 1) : rr * (qq + 1) + (xcd - rr) * qq) + cidx;
  const int gM = M / 256;
  const int m0 = (wg % gM) * 256;
  const int n0 = (wg / gM) * 128;

  const int srow = tid >> 2;               // 0..127
  const int ccol = tid & 3;
  const int skey = (srow >> 1) & 3;
  const int gcol = (ccol ^ skey) * 8;
  const bf16* aS = A + (size_t)(m0 + srow) * K + gcol;
  const bf16* uS = Bu + (size_t)(n0 + srow) * K + gcol;
  const bf16* gSp = Bg + (size_t)(n0 + srow) * K + gcol;
  const int dst0 = tid * 8;

  const int rkey = (r16 >> 1) & 3;
  const int rchunk = (hi ^ rkey) * 8;

  f32x4 accU[8][2] = {}, accG[8][2] = {};
  const int NT = K / 32;

#pragma unroll
  for (int s = 0; s < 3; ++s) {
    gld16(aS + s * 32, &SA[s][dst0]);
    gld16(aS + s * 32 + (size_t)128 * K, &SA[s][dst0 + 4096]);
    gld16(uS + s * 32, &SU[s][dst0]);
    gld16(gSp + s * 32, &SG[s][dst0]);
  }
  asm volatile("s_waitcnt vmcnt(8)" ::: "memory");
  __builtin_amdgcn_s_barrier();
  __builtin_amdgcn_sched_barrier(0);

  for (int s = 0; s < NT; ++s) {
    const int cs = s & 3, ps = (s + 3) & 3;
    const bool pre = (s + 3) < NT;
    const size_t koff = (size_t)(s + 3) * 32;
    bf16x8 af[4], bu[2], bg[2];

#pragma unroll
    for (int j = 0; j < 2; ++j) {
      bu[j] = *(const bf16x8*)&SU[cs][(wn * 32 + j * 16 + r16) * 32 + rchunk];
      bg[j] = *(const bf16x8*)&SG[cs][(wn * 32 + j * 16 + r16) * 32 + rchunk];
    }
#pragma unroll
    for (int i = 0; i < 4; ++i)
      af[i] = *(const bf16x8*)&SA[cs][(wm * 128 + i * 16 + r16) * 32 + rchunk];
    if (pre) {
      gld16(aS + koff, &SA[ps][dst0]);
      gld16(aS + koff + (size_t)128 * K, &SA[ps][dst0 + 4096]);
    }
    __builtin_amdgcn_s_barrier();
    __builtin_amdgcn_sched_barrier(0);
    __builtin_amdgcn_s_setprio(1);
#pragma unroll
    for (int i = 0; i < 4; ++i)
#pragma unroll
      for (int j = 0; j < 2; ++j) {
        accU[i][j] = __builtin_amdgcn_mfma_f32_16x16x32_bf16(af[i], bu[j], accU[i][j], 0, 0, 0);
        accG[i][j] = __builtin_amdgcn_mfma_f32_16x16x32_bf16(af[i], bg[j], accG[i][j], 0, 0, 0);
      }
    __builtin_amdgcn_s_setprio(0);
    __builtin_amdgcn_s_barrier();
    __builtin_amdgcn_sched_barrier(0);

#pragma unroll
    for (int i = 0; i < 4; ++i)
      af[i] = *(const bf16x8*)&SA[cs][(wm * 128 + 64 + i * 16 + r16) * 32 + rchunk];
    if (pre) {
      gld16(uS + koff, &SU[ps][dst0]);
      gld16(gSp + koff, &SG[ps][dst0]);
    }
    __builtin_amdgcn_s_barrier();
    __builtin_amdgcn_sched_barrier(0);
    __builtin_amdgcn_s_setprio(1);
#pragma unroll
    for (int i = 0; i < 4; ++i)
#pragma unroll
      for (int j = 0; j < 2; ++j) {
        accU[4 + i][j] = __builtin_amdgcn_mfma_f32_16x16x32_bf16(af[i], bu[j], accU[4 + i][j], 0, 0, 0);
        accG[4 + i][j] = __builtin_amdgcn_mfma_f32_16x16x32_bf16(af[i], bg[j], accG[4 + i][j], 0, 0, 0);
      }
    __builtin_amdgcn_s_setprio(0);
    if (pre)               asm volatile("s_waitcnt vmcnt(8)" ::: "memory");
    else if ((s + 2) < NT) asm volatile("s_waitcnt vmcnt(4)" ::: "memory");
    else if ((s + 1) < NT) asm volatile("s_waitcnt vmcnt(0)" ::: "memory");
    __builtin_amdgcn_s_barrier();
    __builtin_amdgcn_sched_barrier(0);
  }

#pragma unroll
  for (int mi = 0; mi < 8; ++mi) {
    const int m = m0 + wm * 128 + mi * 16 + hi * 4;
#pragma unroll
    for (int j = 0; j < 2; ++j) {
      const int n = n0 + wn * 32 + j * 16 + r16;
#pragma unroll
      for (int q = 0; q < 4; ++q) {
        float u = accU[mi][j][q];
        float g = accG[mi][j][q];
        float sg = g / (1.0f + __expf(-g));
        Cp[(size_t)(m + q) * N + n] = (bf16)(sg * u);
      }
    }
  }
}

// ---------------- GEMM B: BMxBN ring (generalized; LA/LB staging passes) ----------------

template <int BM, int BN, int WMW, int WNW, int EP>
__global__ __launch_bounds__(WMW * WNW * 64, 2) void gemmk(
    const bf16* __restrict__ A, const bf16* __restrict__ Bt, void* __restrict__ Cp,
    const float* __restrict__ bias, const bf16* __restrict__ aux,
    int M, int N, int K) {
  constexpr int BK = 32;
  constexpr int MF = BM / (WMW * 16);
  constexpr int NF = BN / (WNW * 16);
  constexpr int LA = BM / 64;
  constexpr int LB = BN / 64;
  constexpr int VM_MAIN = 2 * LA + LB;
  constexpr int VM_TAIL = LA + LB;
  __shared__ bf16 sA[4][BM * BK];
  __shared__ bf16 sB[4][BN * BK];

  const int tid = threadIdx.x;
  const int lane = tid & 63;
  const int r16 = lane & 15, hi = lane >> 4;
  const int wave = tid >> 6;
  const int wm = wave / WNW, wn = wave % WNW;

  const int nwg = gridDim.x;
  const int orig = blockIdx.x;
  const int qq = nwg >> 3, rr = nwg & 7;
  const int xcd = orig & 7, cidx = orig >> 3;
  const int wg = (xcd < rr ? xcd * (qq + 1) : rr * (qq + 1) + (xcd - rr) * qq) + cidx;
  const int gM = M / BM;
  const int m0 = (wg % gM) * BM;
  const int n0 = (wg / gM) * BN;

  const int srow = tid >> 2;
  const int ccol = tid & 3;
  const int skey = (srow >> 1) & 3;
  const int gcol = ((ccol ^ skey)) * 8;
  const bf16* aS = A + (size_t)(m0 + srow) * K + gcol;
  const bf16* bS = Bt + (size_t)(n0 + srow) * K + gcol;
  const int dst0 = srow * BK + ccol * 8;

  const int rkey = (r16 >> 1) & 3;
  const int rchunk = (hi ^ rkey) * 8;

  f32x4 acc[MF][NF] = {};
  const int NT = K / BK;

#pragma unroll
  for (int t0_ = 0; t0_ < 2; ++t0_) {
#pragma unroll
    for (int p = 0; p < LA; ++p)
      gld16(aS + t0_ * BK + (size_t)p * 64 * K, &sA[t0_][dst0 + p * 64 * BK]);
#pragma unroll
    for (int p = 0; p < LB; ++p)
      gld16(bS + t0_ * BK + (size_t)p * 64 * K, &sB[t0_][dst0 + p * 64 * BK]);
  }

  for (int t = 0; t < NT; ++t) {
    const int cb = t & 3;
    const int pb = (t + 2) & 3;
    const bool pre = (t + 2) < NT;
    if (pre) {
#pragma unroll
      for (int p = 0; p < LA; ++p)
        gld16(aS + (size_t)(t + 2) * BK + (size_t)p * 64 * K, &sA[pb][dst0 + p * 64 * BK]);
    }
    if (pre)             asm volatile("s_waitcnt vmcnt(%0)" :: "i"(VM_MAIN) : "memory");
    else if (t + 1 < NT) asm volatile("s_waitcnt vmcnt(%0)" :: "i"(VM_TAIL) : "memory");
    else                 asm volatile("s_waitcnt vmcnt(0)" ::: "memory");
    __builtin_amdgcn_s_barrier();
    __builtin_amdgcn_sched_barrier(0);

    bf16x8 bf_[NF];
#pragma unroll
    for (int j = 0; j < NF; ++j)
      bf_[j] = *(const bf16x8*)&sB[cb][(wn * (NF * 16) + j * 16 + r16) * BK + rchunk];
    if (pre) {
#pragma unroll
      for (int p = 0; p < LB; ++p)
        gld16(bS + (size_t)(t + 2) * BK + (size_t)p * 64 * K, &sB[pb][dst0 + p * 64 * BK]);
    }
    bf16x8 af[MF];
#pragma unroll
    for (int i = 0; i < MF; ++i)
      af[i] = *(const bf16x8*)&sA[cb][(wm * (MF * 16) + i * 16 + r16) * BK + rchunk];
    __builtin_amdgcn_s_setprio(1);
#pragma unroll
    for (int i = 0; i < MF; ++i)
#pragma unroll
      for (int j = 0; j < NF; ++j)
        acc[i][j] = __builtin_amdgcn_mfma_f32_16x16x32_bf16(af[i], bf_[j], acc[i][j], 0, 0, 0);
    __builtin_amdgcn_s_setprio(0);
  }

#pragma unroll
  for (int i = 0; i < MF; ++i) {
    const int m = m0 + wm * (MF * 16) + i * 16 + hi * 4;
#pragma unroll
    for (int j = 0; j < NF; ++j) {
      const int n = n0 + wn * (NF * 16) + j * 16 + r16;
#pragma unroll
      for (int q = 0; q < 4; ++q) {
        size_t idx = (size_t)(m + q) * N + n;
        float v = acc[i][j][q];
        if constexpr (EP == EP_F32) {
          ((float*)Cp)[idx] = v;
        } else if constexpr (EP == EP_F32_BIAS) {
          ((float*)Cp)[idx] = v + bias[n];
        } else if constexpr (EP == EP_BF16) {
          ((bf16*)Cp)[idx] = (bf16)v;
        } else if constexpr (EP == EP_BF16_BIAS) {
          ((bf16*)Cp)[idx] = (bf16)(v + bias[n]);
        } else {
          float sg = v / (1.0f + __expf(-v));
          ((bf16*)Cp)[idx] = (bf16)(sg * (float)aux[idx]);
        }
      }
    }
  }
}

// ---------------- flash attention: swapped QK^T, QBLK=128 (2 Q-frags/wave) ----------------

__global__ __launch_bounds__(256, 2) void attn_flash(
    const bf16* __restrict__ Qp, const bf16* __restrict__ Kp, int ldk,
    const bf16* __restrict__ Vt, bf16* __restrict__ Op) {
  __shared__ bf16 Ks[2][128 * 32];
  __shared__ bf16 Vs[4][64 * 32];
  __shared__ bf16 Ps[4][2][16 * 144];
  const int tid = threadIdx.x, lane = tid & 63, wave = tid >> 6;
  const int h = blockIdx.y, b = blockIdx.z;
  const int r16 = lane & 15, hi = lane >> 4;
  const int qbase = blockIdx.x * 128 + wave * 32;

  const float QS = 0.1803368801f;          // 0.125 * log2(e)
  bf16x8 qa[2][2];
#pragma unroll
  for (int f = 0; f < 2; ++f) {
    const bf16* qp = Qp + (size_t)(b * TT + qbase + f * 16 + r16) * ldk + h * DH + hi * 8;
    bf16x8 q0 = *(const bf16x8*)qp;
    bf16x8 q1 = *(const bf16x8*)(qp + 32);
#pragma unroll
    for (int e = 0; e < 8; ++e) {
      qa[f][0][e] = (bf16)((float)q0[e] * QS);
      qa[f][1][e] = (bf16)((float)q1[e] * QS);
    }
  }
  const bf16* kBase = Kp + (size_t)(b * TT) * ldk + h * DH;
  const bf16* vBase = Vt + (size_t)(b * NH + h) * DH * TT;

  const int srow = tid >> 2, ccol = tid & 3;
  const int skey = (srow >> 1) & 3;
  const int scolS = (ccol ^ skey) * 8;
  const int dstc = ccol * 8;
  const int rkey = (r16 >> 1) & 3;
  const int rchunk = (hi ^ rkey) * 8;

  float m_run[2] = {-1e30f, -1e30f};
  float l_run[2] = {0.f, 0.f};
  f32x4 oacc[2][4] = {};

  for (int kt = 0; kt < TT; kt += 128) {
#pragma unroll
    for (int half = 0; half < 2; ++half) {
      gld16(kBase + (size_t)(kt + srow) * ldk + half * 32 + scolS, &Ks[half][srow * 32 + dstc]);
      gld16(kBase + (size_t)(kt + 64 + srow) * ldk + half * 32 + scolS, &Ks[half][(64 + srow) * 32 + dstc]);
    }
#pragma unroll
    for (int ks = 0; ks < 4; ++ks)
      gld16(vBase + (size_t)srow * TT + kt + ks * 32 + scolS, &Vs[ks][srow * 32 + dstc]);
    __syncthreads();

#pragma unroll
    for (int f = 0; f < 2; ++f) {
      f32x4 s[8];
      __builtin_amdgcn_s_setprio(1);
#pragma unroll
      for (int kg = 0; kg < 8; ++kg) {
        f32x4 z = {};
        bf16x8 kb0 = *(const bf16x8*)&Ks[0][(kg * 16 + r16) * 32 + rchunk];
        bf16x8 kb1 = *(const bf16x8*)&Ks[1][(kg * 16 + r16) * 32 + rchunk];
        z = __builtin_amdgcn_mfma_f32_16x16x32_bf16(kb0, qa[f][0], z, 0, 0, 0);
        z = __builtin_amdgcn_mfma_f32_16x16x32_bf16(kb1, qa[f][1], z, 0, 0, 0);
        s[kg] = z;
      }
      __builtin_amdgcn_s_setprio(0);

      float pm = s[0][0];
#pragma unroll
      for (int kg = 0; kg < 8; ++kg)
#pragma unroll
        for (int i = 0; i < 4; ++i) pm = fmaxf(pm, s[kg][i]);
      pm = fmaxf(pm, __shfl_xor(pm, 16));
      pm = fmaxf(pm, __shfl_xor(pm, 32));

      if (!__all(pm - m_run[f] <= 11.5411f)) {
        float mnew = fmaxf(m_run[f], pm);
        float fr = exp2f(m_run[f] - mnew);
        m_run[f] = mnew;
        l_run[f] *= fr;
#pragma unroll
        for (int i = 0; i < 4; ++i) {
          float fi = __shfl(fr, hi * 4 + i);
#pragma unroll
          for (int n = 0; n < 4; ++n) oacc[f][n][i] *= fi;
        }
      }

      float lsum = 0.f;
#pragma unroll
      for (int kg = 0; kg < 8; ++kg) {
        float p0 = exp2f(s[kg][0] - m_run[f]);
        float p1 = exp2f(s[kg][1] - m_run[f]);
        float p2 = exp2f(s[kg][2] - m_run[f]);
        float p3 = exp2f(s[kg][3] - m_run[f]);
        lsum += (p0 + p1) + (p2 + p3);
        bf16x4 pk = {(bf16)p0, (bf16)p1, (bf16)p2, (bf16)p3};
        *(bf16x4*)&Ps[wave][f][r16 * 144 + kg * 16 + hi * 4] = pk;
      }
      l_run[f] += lsum;

      __builtin_amdgcn_s_setprio(1);
#pragma unroll
      for (int ks = 0; ks < 4; ++ks) {
        bf16x8 pa = *(const bf16x8*)&Ps[wave][f][r16 * 144 + ks * 32 + hi * 8];
#pragma unroll
        for (int n = 0; n < 4; ++n) {
          bf16x8 vb = *(const bf16x8*)&Vs[ks][(n * 16 + r16) * 32 + rchunk];
          oacc[f][n] = __builtin_amdgcn_mfma_f32_16x16x32_bf16(pa, vb, oacc[f][n], 0, 0, 0);
        }
      }
      __builtin_amdgcn_s_setprio(0);
    }
    __syncthreads();
  }

#pragma unroll
  for (int f = 0; f < 2; ++f) {
    float lq = l_run[f];
    lq += __shfl_xor(lq, 16);
    lq += __shfl_xor(lq, 32);
    float invq = 1.0f / lq;
#pragma unroll
    for (int i = 0; i < 4; ++i) {
      float inv_i = __shfl(invq, hi * 4 + i);
      int trow = qbase + f * 16 + hi * 4 + i;
      size_t base = ((size_t)b * TT + trow) * DIM + h * DH;
#pragma unroll
      for (int n = 0; n < 4; ++n)
        Op[base + n * 16 + r16] = (bf16)(oacc[f][n][i] * inv_i);
    }
  }
}

// ---------------- residual + rmsnorm (y is bf16: GEMM outputs rounded once;
// residual accumulation itself stays fp32 via xf) ----------------

__global__ __launch_bounds__(256) void resid_rms(
    const float* __restrict__ xin, const bf16* __restrict__ y, const float* __restrict__ wgt,
    float* __restrict__ xf_out, bf16* __restrict__ xb_out) {
  __shared__ float red[4];
  const int r = blockIdx.x, tid = threadIdx.x;
  const size_t base = (size_t)r * DIM + tid * 4;
  float4 v = *(const float4*)(xin + base);
  bf16x4 ub = *(const bf16x4*)(y + base);
  v.x += (float)ub[0]; v.y += (float)ub[1]; v.z += (float)ub[2]; v.w += (float)ub[3];
  float ss = v.x * v.x + v.y * v.y + v.z * v.z + v.w * v.w;
#pragma unroll
  for (int d = 1; d < 64; d <<= 1) ss += __shfl_xor(ss, d);
  if ((tid & 63) == 0) red[tid >> 6] = ss;
  __syncthreads();
  ss = red[0] + red[1] + red[2] + red[3];
  float sc = rsqrtf(ss * (1.0f / DIM) + 1e-8f);
  const float4 wv = *(const float4*)(wgt + tid * 4);
  float o0 = v.x * sc * wv.x, o1 = v.y * sc * wv.y, o2 = v.z * sc * wv.z, o3 = v.w * sc * wv.w;
  if (xf_out) {
    float4 ov = {o0, o1, o2, o3};
    *(float4*)(xf_out + base) = ov;
  }
  bf16x4 ob = {(bf16)o0, (bf16)o1, (bf16)o2, (bf16)o3};
  *(bf16x4*)(xb_out + base) = ob;
}

// ---------------- slot softmax rows (scale D^-0.5 = 1/32) ----------------

__global__ __launch_bounds__(256) void softmax_rows(const float* __restrict__ Sc, bf16* __restrict__ P) {
  __shared__ float red[4];
  const int r = blockIdx.x, tid = threadIdx.x;
  const float* row = Sc + (size_t)r * NSLOT;
  float4 v[4];
#pragma unroll
  for (int i = 0; i < 4; ++i) v[i] = *(const float4*)(row + tid * 4 + i * 1024);
  float mx = -1e30f;
#pragma unroll
  for (int i = 0; i < 4; ++i)
    mx = fmaxf(fmaxf(fmaxf(fmaxf(mx, v[i].x), v[i].y), v[i].z), v[i].w);
#pragma unroll
  for (int d = 1; d < 64; d <<= 1) mx = fmaxf(mx, __shfl_xor(mx, d));
  if ((tid & 63) == 0) red[tid >> 6] = mx;
  __syncthreads();
  mx = fmaxf(fmaxf(red[0], red[1]), fmaxf(red[2], red[3]));
  __syncthreads();
  float e[16];
  float sum = 0.f;
#pragma unroll
  for (int i = 0; i < 4; ++i) {
    e[i * 4 + 0] = __expf((v[i].x - mx) * 0.03125f);
    e[i * 4 + 1] = __expf((v[i].y - mx) * 0.03125f);
    e[i * 4 + 2] = __expf((v[i].z - mx) * 0.03125f);
    e[i * 4 + 3] = __expf((v[i].w - mx) * 0.03125f);
    sum += e[i * 4 + 0] + e[i * 4 + 1] + e[i * 4 + 2] + e[i * 4 + 3];
  }
#pragma unroll
  for (int d = 1; d < 64; d <<= 1) sum += __shfl_xor(sum, d);
  if ((tid & 63) == 0) red[tid >> 6] = sum;
  __syncthreads();
  sum = red[0] + red[1] + red[2] + red[3];
  float inv = 1.0f / sum;
#pragma unroll
  for (int i = 0; i < 4; ++i) {
    bf16x4 ob = {(bf16)(e[i * 4 + 0] * inv), (bf16)(e[i * 4 + 1] * inv),
                 (bf16)(e[i * 4 + 2] * inv), (bf16)(e[i * 4 + 3] * inv)};
    *(bf16x4*)(P + (size_t)r * NSLOT + tid * 4 + i * 1024) = ob;
  }
}

// ---------------- host orchestration ----------------

extern "C" void kernel_launch(void* const* d_in, const int* in_sizes, int n_in,
                              void* d_out, int out_size, void* d_ws, size_t ws_size,
                              hipStream_t stream) {
  (void)in_sizes; (void)n_in; (void)out_size;
  const int* ids = (const int*)d_in[0];
  const float* emb = (const float*)d_in[1];
  const float* Wq = (const float*)d_in[2];
  const float* Wk = (const float*)d_in[3];
  const float* Wv = (const float*)d_in[4];
  const float* Wo = (const float*)d_in[5];
  const float* bo = (const float*)d_in[6];
  const float* n1 = (const float*)d_in[7];
  const float* Wg = (const float*)d_in[8];
  const float* Wu = (const float*)d_in[9];
  const float* Wd = (const float*)d_in[10];
  const float* n2 = (const float*)d_in[11];
  const float* memp = (const float*)d_in[12];
  const float* Wsp = (const float*)d_in[13];
  const float* bsp = (const float*)d_in[14];
  const float* Wrp = (const float*)d_in[15];
  const float* brp = (const float*)d_in[16];
  const float* nout = (const float*)d_in[17];

  char* w = (char*)d_ws;
  auto alloc = [&](size_t bytes) -> void* {
    void* p = (void*)w;
    w += (bytes + 255) & ~(size_t)255;
    return p;
  };

  const size_t dd = (size_t)DIM * DIM;
  const size_t dff = (size_t)DIM * FFD;

  bf16* tok_b = (bf16*)alloc((size_t)NV * DIM * 2);
  bf16* mem_b = (bf16*)alloc((size_t)NSLOT * DIM * 2);
  bf16* memT  = (bf16*)alloc((size_t)NSLOT * DIM * 2);
  bf16* WspT  = (bf16*)alloc(dd * 2);
  bf16* WrpT  = (bf16*)alloc(dd * 2);
  float* xf   = (float*)alloc((size_t)BT * DIM * 4);
  bf16* xb    = (bf16*)alloc((size_t)BT * DIM * 2);
  bf16* yb    = (bf16*)alloc((size_t)BT * DIM * 2);   // GEMM outputs, bf16
  bf16* W3T   = (bf16*)alloc(3 * dd * 2);   // [WqT | WkT | WvT] rows
  bf16* WoT   = (bf16*)alloc(dd * 2);
  bf16* WgT   = (bf16*)alloc(dff * 2);
  bf16* WuT   = (bf16*)alloc(dff * 2);
  bf16* WdT   = (bf16*)alloc(dff * 2);
  bf16* qkv   = (bf16*)alloc((size_t)BT * 3 * DIM * 2);
  bf16* vT_   = (bf16*)alloc((size_t)BT * DIM * 2);
  bf16* ot_   = (bf16*)alloc((size_t)BT * DIM * 2);
  bf16* qb    = (bf16*)alloc((size_t)BT * DIM * 2);
  bf16* rb    = (bf16*)alloc((size_t)BT * DIM * 2);
  bf16* hb    = (bf16*)alloc((size_t)BT * DIM * 2);

  size_t used = (size_t)(w - (char*)d_ws);
  size_t region_bytes = (size_t)BT * NSLOT * 4 + (size_t)BT * NSLOT * 2;
  char* region;
  if (used + region_bytes <= ws_size) region = (char*)alloc(region_bytes);
  else region = (char*)d_out;
  bf16* Hb = (bf16*)region;
  float* scoresF = (float*)region;
  bf16* attnb = (bf16*)(region + (size_t)BT * NSLOT * 4);

  dim3 blkT(8, 32);
  dim3 blkV(32, 8);

  cvt_bf16<<<NV * DIM / 1024, 256, 0, stream>>>(emb, tok_b, (long)NV * DIM);
  cvt_bf16<<<NSLOT * DIM / 1024, 256, 0, stream>>>(memp, mem_b, (long)NSLOT * DIM);
  {
    TBatch tb{};
    tb.src[0] = memp; tb.dst[0] = memT; tb.R[0] = NSLOT; tb.C[0] = DIM; tb.base[0] = 0;
    tb.src[1] = Wsp;  tb.dst[1] = WspT; tb.R[1] = DIM;   tb.C[1] = DIM; tb.base[1] = 4096;
    tb.src[2] = Wrp;  tb.dst[2] = WrpT; tb.R[2] = DIM;   tb.C[2] = DIM; tb.base[2] = 5120;
    for (int i = 3; i < 7; ++i) { tb.base[i] = 0x7fffffff; tb.src[i] = memp; tb.dst[i] = memT; tb.R[i] = 32; tb.C[i] = 32; }
    transpose_cvt_batch<<<6144, blkT, 0, stream>>>(tb);
  }
  embed_rope<<<BT, 256, 0, stream>>>(ids, emb, xf, xb);

  for (int l = 0; l < NL; ++l) {
    {
      TBatch tb{};
      tb.src[0] = Wq + l * dd;  tb.dst[0] = W3T;          tb.R[0] = DIM; tb.C[0] = DIM;  tb.base[0] = 0;
      tb.src[1] = Wk + l * dd;  tb.dst[1] = W3T + dd;     tb.R[1] = DIM; tb.C[1] = DIM;  tb.base[1] = 1024;
      tb.src[2] = Wv + l * dd;  tb.dst[2] = W3T + 2 * dd; tb.R[2] = DIM; tb.C[2] = DIM;  tb.base[2] = 2048;
      tb.src[3] = Wo + l * dd;  tb.dst[3] = WoT;          tb.R[3] = DIM; tb.C[3] = DIM;  tb.base[3] = 3072;
      tb.src[4] = Wg + l * dff; tb.dst[4] = WgT;          tb.R[4] = DIM; tb.C[4] = FFD;  tb.base[4] = 4096;
      tb.src[5] = Wu + l * dff; tb.dst[5] = WuT;          tb.R[5] = DIM; tb.C[5] = FFD;  tb.base[5] = 8192;
      tb.src[6] = Wd + l * dff; tb.dst[6] = WdT;          tb.R[6] = FFD; tb.C[6] = DIM;  tb.base[6] = 12288;
      transpose_cvt_batch<<<16384, blkT, 0, stream>>>(tb);
    }

    gemm8<EP_BF16><<<dim3(16 * 12), 512, 0, stream>>>(
        xb, W3T, qkv, nullptr, nullptr, BT, 3 * DIM, DIM);
    transpose_v<<<dim3(TT / 32, DH / 32, BB * NH), blkV, 0, stream>>>(qkv + 2 * DIM, 3 * DIM, vT_);
    attn_flash<<<dim3(TT / 128, NH, BB), 256, 0, stream>>>(qkv, qkv + DIM, 3 * DIM, vT_, ot_);
    gemmk<128, 64, 2, 2, EP_BF16_BIAS><<<dim3(32 * 16), 256, 0, stream>>>(
        ot_, WoT, yb, bo + l * DIM, nullptr, BT, DIM, DIM);
    resid_rms<<<BT, 256, 0, stream>>>(xf, yb, n1 + l * DIM, xf, xb);
    gemm8ff<<<dim3(16 * 32), 512, 0, stream>>>(
        xb, WuT, WgT, Hb, BT, FFD, DIM);
    gemmk<128, 64, 2, 2, EP_BF16><<<dim3(32 * 16), 256, 0, stream>>>(
        Hb, WdT, yb, nullptr, nullptr, BT, DIM, FFD);
    resid_rms<<<BT, 256, 0, stream>>>(xf, yb, n2 + l * DIM, xf, xb);
  }

  gemmk<128, 64, 2, 2, EP_BF16_BIAS><<<dim3(32 * 16), 256, 0, stream>>>(
      xb, WspT, qb, bsp, nullptr, BT, DIM, DIM);
  gemm8<EP_F32><<<dim3(16 * 16), 512, 0, stream>>>(
      qb, mem_b, scoresF, nullptr, nullptr, BT, NSLOT, DIM);
  softmax_rows<<<BT, 256, 0, stream>>>(scoresF, attnb);
  gemmk<128, 64, 2, 2, EP_BF16><<<dim3(32 * 16), 256, 0, stream>>>(
      attnb, memT, rb, nullptr, nullptr, BT, DIM, NSLOT);
  gemmk<128, 64, 2, 2, EP_BF16_BIAS><<<dim3(32 * 16), 256, 0, stream>>>(
      rb, WrpT, yb, brp, nullptr, BT, DIM, DIM);
  resid_rms<<<BT, 256, 0, stream>>>(xf, yb, nout, nullptr, hb);
  gemm8<EP_F32><<<dim3(16 * 125), 512, 0, stream>>>(
      hb, tok_b, (float*)d_out, nullptr, nullptr, BT, NV, DIM);
}

// Round 16
// 2591.476 us; speedup vs baseline: 1.0791x; 1.0033x over previous
//
#include <hip/hip_runtime.h>

typedef __bf16 bf16;
typedef __attribute__((ext_vector_type(8))) __bf16 bf16x8;
typedef __attribute__((ext_vector_type(4))) __bf16 bf16x4;
typedef __attribute__((ext_vector_type(4))) float f32x4;

#define NL 6
#define DIM 1024
#define NH 16
#define DH 64
#define TT 2048
#define BB 2
#define BT 4096
#define FFD 4096
#define NSLOT 4096
#define NV 32000

__device__ __forceinline__ void gld16(const void* g, void* l) {
  __builtin_amdgcn_global_load_lds(
      (const __attribute__((address_space(1))) void*)g,
      (__attribute__((address_space(3))) void*)l, 16, 0, 0);
}

// ---------------- conversion / transpose kernels ----------------

__global__ void cvt_bf16(const float* __restrict__ s, bf16* __restrict__ d, long n) {
  long i = ((long)blockIdx.x * 256 + threadIdx.x) * 4;
  if (i + 3 < n) {
    float4 v = *(const float4*)(s + i);
    bf16x4 o = {(bf16)v.x, (bf16)v.y, (bf16)v.z, (bf16)v.w};
    *(bf16x4*)(d + i) = o;
  }
}

// Batched transpose: up to 7 segments in one launch (verified R12 body).
// NOTE (R13 lesson): keep per-layer (not hoisted) — the transpose doubles as
// an L3 prefetch of the layer's weights; hoisting all layers evicts and
// forces cold HBM weight reads (+163 us measured).
struct TBatch {
  const float* src[7];
  bf16* dst[7];
  int R[7], C[7];
  int base[7];
};

__global__ void transpose_cvt_batch(TBatch tb) {
  const int bid = blockIdx.x;
  int s = 0;
#pragma unroll
  for (int i = 1; i < 7; ++i)
    if (bid >= tb.base[i]) s = i;
  const int local = bid - tb.base[s];
  const int R = tb.R[s], C = tb.C[s];
  const float* __restrict__ src = tb.src[s];
  bf16* __restrict__ dst = tb.dst[s];
  const int tilesPerRow = C / 32;
  const int c0 = (local % tilesPerRow) * 32;
  const int r0 = (local / tilesPerRow) * 32;

  __shared__ float tile[32][33];
  int tx = threadIdx.x;  // 0..7
  int ty = threadIdx.y;  // 0..31
  float4 v = *(const float4*)(src + (size_t)(r0 + ty) * C + c0 + tx * 4);
  tile[ty][tx * 4 + 0] = v.x;
  tile[ty][tx * 4 + 1] = v.y;
  tile[ty][tx * 4 + 2] = v.z;
  tile[ty][tx * 4 + 3] = v.w;
  __syncthreads();
  bf16x4 o = {(bf16)tile[tx * 4 + 0][ty], (bf16)tile[tx * 4 + 1][ty],
              (bf16)tile[tx * 4 + 2][ty], (bf16)tile[tx * 4 + 3][ty]};
  *(bf16x4*)(dst + (size_t)(c0 + ty) * R + r0 + tx * 4) = o;
}

// v [b*T+t][ldv stride, h*DH+dh] bf16 -> vT [(b*NH+h)*DH+dh][t] bf16
__global__ void transpose_v(const bf16* __restrict__ v, int ldv, bf16* __restrict__ vT) {
  __shared__ bf16 tile[32][33];
  int t0 = blockIdx.x * 32, d0 = blockIdx.y * 32, bh = blockIdx.z;
  int b = bh >> 4, h = bh & 15;
  int tx = threadIdx.x, ty = threadIdx.y;
#pragma unroll
  for (int i = 0; i < 4; ++i)
    tile[ty + i * 8][tx] = v[(size_t)(b * TT + t0 + ty + i * 8) * ldv + h * DH + d0 + tx];
  __syncthreads();
#pragma unroll
  for (int i = 0; i < 4; ++i)
    vT[((size_t)bh * DH + d0 + ty + i * 8) * TT + t0 + tx] = tile[tx][ty + i * 8];
}

// ---------------- embedding + rope ----------------

__global__ void embed_rope(const int* __restrict__ ids, const float* __restrict__ emb,
                           float* __restrict__ xf, bf16* __restrict__ xb) {
  int bt = blockIdx.x;
  int t = bt & (TT - 1);
  int id = ids[bt];
  const float* row = emb + (size_t)id * DIM;
  for (int p = threadIdx.x; p < DIM / 2; p += 256) {
    float x1 = row[2 * p], x2 = row[2 * p + 1];
    float inv = __expf(-9.210340371976184f * (float)p * (1.0f / 512.0f));
    float ang = (float)t * inv;
    float c = cosf(ang), s = sinf(ang);
    float o1 = x1 * c - x2 * s;
    float o2 = x1 * s + x2 * c;
    size_t base = (size_t)bt * DIM + 2 * p;
    xf[base] = o1; xf[base + 1] = o2;
    xb[base] = (bf16)o1; xb[base + 1] = (bf16)o2;
  }
}

enum { EP_BF16 = 0, EP_F32 = 1, EP_F32_BIAS = 2, EP_BF16_BIAS = 3, EP_SILU_MUL = 4 };

// ---------------- GEMM A: 256x256, 4-slot half-K ring, 512 thr (frozen) ----------------

template <int EP>
__global__ __launch_bounds__(512, 1) void gemm8(
    const bf16* __restrict__ A, const bf16* __restrict__ Bt, void* __restrict__ Cp,
    const float* __restrict__ bias, const bf16* __restrict__ aux,
    int M, int N, int K) {
  __shared__ bf16 S[4][2][256 * 32];   // [slot][A=0/B=1][256 rows x 32] = 128 KiB

  const int tid = threadIdx.x;
  const int lane = tid & 63;
  const int r16 = lane & 15, hi = lane >> 4;
  const int wave = tid >> 6;
  const int wm = wave >> 2, wn = wave & 3;

  const int nwg = gridDim.x;
  const int orig = blockIdx.x;
  const int qq = nwg >> 3, rr = nwg & 7;
  const int xcd = orig & 7, cidx = orig >> 3;
  const int wg = (xcd < rr ? xcd * (qq + 1) : rr * (qq + 1) + (xcd - rr) * qq) + cidx;
  const int gM = M / 256;
  const int m0 = (wg % gM) * 256;
  const int n0 = (wg / gM) * 256;

  const int srow = tid >> 2;               // 0..127
  const int ccol = tid & 3;
  const int skey = (srow >> 1) & 3;
  const int gcol = (ccol ^ skey) * 8;      // pre-swizzled global col
  const bf16* aS = A + (size_t)(m0 + srow) * K + gcol;
  const bf16* bS = Bt + (size_t)(n0 + srow) * K + gcol;
  const int dst0 = tid * 8;                // linear LDS dest

  const int rkey = (r16 >> 1) & 3;
  const int rchunk = (hi ^ rkey) * 8;

  f32x4 acc[8][4] = {};
  const int NT = K / 32;

#pragma unroll
  for (int s = 0; s < 3; ++s) {
    gld16(aS + s * 32, &S[s][0][dst0]);
    gld16(aS + s * 32 + (size_t)128 * K, &S[s][0][dst0 + 4096]);
    gld16(bS + s * 32, &S[s][1][dst0]);
    gld16(bS + s * 32 + (size_t)128 * K, &S[s][1][dst0 + 4096]);
  }
  asm volatile("s_waitcnt vmcnt(8)" ::: "memory");
  __builtin_amdgcn_s_barrier();
  __builtin_amdgcn_sched_barrier(0);

  for (int s = 0; s < NT; ++s) {
    const int cs = s & 3, ps = (s + 3) & 3;
    const bool pre = (s + 3) < NT;
    const bf16* SA = S[cs][0];
    const bf16* SB = S[cs][1];
    const size_t koff = (size_t)(s + 3) * 32;
    bf16x8 af[4], bfr[4];

#pragma unroll
    for (int j = 0; j < 4; ++j)
      bfr[j] = *(const bf16x8*)&SB[(wn * 64 + j * 16 + r16) * 32 + rchunk];
#pragma unroll
    for (int i = 0; i < 4; ++i)
      af[i] = *(const bf16x8*)&SA[(wm * 128 + i * 16 + r16) * 32 + rchunk];
    if (pre) {
      gld16(aS + koff, &S[ps][0][dst0]);
      gld16(aS + koff + (size_t)128 * K, &S[ps][0][dst0 + 4096]);
    }
    __builtin_amdgcn_s_barrier();
    __builtin_amdgcn_sched_barrier(0);
    __builtin_amdgcn_s_setprio(1);
#pragma unroll
    for (int i = 0; i < 4; ++i)
#pragma unroll
      for (int j = 0; j < 4; ++j)
        acc[i][j] = __builtin_amdgcn_mfma_f32_16x16x32_bf16(af[i], bfr[j], acc[i][j], 0, 0, 0);
    __builtin_amdgcn_s_setprio(0);
    __builtin_amdgcn_s_barrier();
    __builtin_amdgcn_sched_barrier(0);

#pragma unroll
    for (int i = 0; i < 4; ++i)
      af[i] = *(const bf16x8*)&SA[(wm * 128 + 64 + i * 16 + r16) * 32 + rchunk];
    if (pre) {
      gld16(bS + koff, &S[ps][1][dst0]);
      gld16(bS + koff + (size_t)128 * K, &S[ps][1][dst0 + 4096]);
    }
    __builtin_amdgcn_s_barrier();
    __builtin_amdgcn_sched_barrier(0);
    __builtin_amdgcn_s_setprio(1);
#pragma unroll
    for (int i = 0; i < 4; ++i)
#pragma unroll
      for (int j = 0; j < 4; ++j)
        acc[4 + i][j] = __builtin_amdgcn_mfma_f32_16x16x32_bf16(af[i], bfr[j], acc[4 + i][j], 0, 0, 0);
    __builtin_amdgcn_s_setprio(0);
    if (pre)               asm volatile("s_waitcnt vmcnt(8)" ::: "memory");
    else if ((s + 2) < NT) asm volatile("s_waitcnt vmcnt(4)" ::: "memory");
    else if ((s + 1) < NT) asm volatile("s_waitcnt vmcnt(0)" ::: "memory");
    __builtin_amdgcn_s_barrier();
    __builtin_amdgcn_sched_barrier(0);
  }

#pragma unroll
  for (int mi = 0; mi < 8; ++mi) {
    const int m = m0 + wm * 128 + mi * 16 + hi * 4;
#pragma unroll
    for (int j = 0; j < 4; ++j) {
      const int n = n0 + wn * 64 + j * 16 + r16;
#pragma unroll
      for (int q = 0; q < 4; ++q) {
        size_t idx = (size_t)(m + q) * N + n;
        float v = acc[mi][j][q];
        if constexpr (EP == EP_F32) {
          ((float*)Cp)[idx] = v;
        } else if constexpr (EP == EP_F32_BIAS) {
          ((float*)Cp)[idx] = v + bias[n];
        } else if constexpr (EP == EP_BF16) {
          ((bf16*)Cp)[idx] = (bf16)v;
        } else if constexpr (EP == EP_BF16_BIAS) {
          ((bf16*)Cp)[idx] = (bf16)(v + bias[n]);
        } else {
          float sg = v / (1.0f + __expf(-v));
          ((bf16*)Cp)[idx] = (bf16)(sg * (float)aux[idx]);
        }
      }
    }
  }
}

// ---------------- GEMM A-FF: fused dual-B (Wu,Wg) 256x128, silu epilogue ----------------

__global__ __launch_bounds__(512, 1) void gemm8ff(
    const bf16* __restrict__ A, const bf16* __restrict__ Bu, const bf16* __restrict__ Bg,
    bf16* __restrict__ Cp, int M, int N, int K) {
  __shared__ bf16 SA[4][256 * 32];   // 64 KiB
  __shared__ bf16 SU[4][128 * 32];   // 32 KiB
  __shared__ bf16 SG[4][128 * 32];   // 32 KiB

  const int tid = threadIdx.x;
  const int lane = tid & 63;
  const int r16 = lane & 15, hi = lane >> 4;
  const int wave = tid >> 6;
  const int wm = wave >> 2, wn = wave & 3;

  const int nwg = gridDim.x;
  const int orig = blockIdx.x;
  const int qq = nwg >> 3, rr = nwg & 7;
  const int xcd = orig & 7, cidx = orig >> 3;
  const int wg = (xcd < rr ? xcd * (qq + 1) : rr * (qq + 1) + (xcd - rr) * qq) + cidx;
  const int gM = M / 256;
  const int m0 = (wg % gM) * 256;
  const int n0 = (wg / gM) * 128;

  const int srow = tid >> 2;               // 0..127
  const int ccol = tid & 3;
  const int skey = (srow >> 1) & 3;
  const int gcol = (ccol ^ skey) * 8;
  const bf16* aS = A + (size_t)(m0 + srow) * K + gcol;
  const bf16* uS = Bu + (size_t)(n0 + srow) * K + gcol;
  const bf16* gSp = Bg + (size_t)(n0 + srow) * K + gcol;
  const int dst0 = tid * 8;

  const int rkey = (r16 >> 1) & 3;
  const int rchunk = (hi ^ rkey) * 8;

  f32x4 accU[8][2] = {}, accG[8][2] = {};
  const int NT = K / 32;

#pragma unroll
  for (int s = 0; s < 3; ++s) {
    gld16(aS + s * 32, &SA[s][dst0]);
    gld16(aS + s * 32 + (size_t)128 * K, &SA[s][dst0 + 4096]);
    gld16(uS + s * 32, &SU[s][dst0]);
    gld16(gSp + s * 32, &SG[s][dst0]);
  }
  asm volatile("s_waitcnt vmcnt(8)" ::: "memory");
  __builtin_amdgcn_s_barrier();
  __builtin_amdgcn_sched_barrier(0);

  for (int s = 0; s < NT; ++s) {
    const int cs = s & 3, ps = (s + 3) & 3;
    const bool pre = (s + 3) < NT;
    const size_t koff = (size_t)(s + 3) * 32;
    bf16x8 af[4], bu[2], bg[2];

#pragma unroll
    for (int j = 0; j < 2; ++j) {
      bu[j] = *(const bf16x8*)&SU[cs][(wn * 32 + j * 16 + r16) * 32 + rchunk];
      bg[j] = *(const bf16x8*)&SG[cs][(wn * 32 + j * 16 + r16) * 32 + rchunk];
    }
#pragma unroll
    for (int i = 0; i < 4; ++i)
      af[i] = *(const bf16x8*)&SA[cs][(wm * 128 + i * 16 + r16) * 32 + rchunk];
    if (pre) {
      gld16(aS + koff, &SA[ps][dst0]);
      gld16(aS + koff + (size_t)128 * K, &SA[ps][dst0 + 4096]);
    }
    __builtin_amdgcn_s_barrier();
    __builtin_amdgcn_sched_barrier(0);
    __builtin_amdgcn_s_setprio(1);
#pragma unroll
    for (int i = 0; i < 4; ++i)
#pragma unroll
      for (int j = 0; j < 2; ++j) {
        accU[i][j] = __builtin_amdgcn_mfma_f32_16x16x32_bf16(af[i], bu[j], accU[i][j], 0, 0, 0);
        accG[i][j] = __builtin_amdgcn_mfma_f32_16x16x32_bf16(af[i], bg[j], accG[i][j], 0, 0, 0);
      }
    __builtin_amdgcn_s_setprio(0);
    __builtin_amdgcn_s_barrier();
    __builtin_amdgcn_sched_barrier(0);

#pragma unroll
    for (int i = 0; i < 4; ++i)
      af[i] = *(const bf16x8*)&SA[cs][(wm * 128 + 64 + i * 16 + r16) * 32 + rchunk];
    if (pre) {
      gld16(uS + koff, &SU[ps][dst0]);
      gld16(gSp + koff, &SG[ps][dst0]);
    }
    __builtin_amdgcn_s_barrier();
    __builtin_amdgcn_sched_barrier(0);
    __builtin_amdgcn_s_setprio(1);
#pragma unroll
    for (int i = 0; i < 4; ++i)
#pragma unroll
      for (int j = 0; j < 2; ++j) {
        accU[4 + i][j] = __builtin_amdgcn_mfma_f32_16x16x32_bf16(af[i], bu[j], accU[4 + i][j], 0, 0, 0);
        accG[4 + i][j] = __builtin_amdgcn_mfma_f32_16x16x32_bf16(af[i], bg[j], accG[4 + i][j], 0, 0, 0);
      }
    __builtin_amdgcn_s_setprio(0);
    if (pre)               asm volatile("s_waitcnt vmcnt(8)" ::: "memory");
    else if ((s + 2) < NT) asm volatile("s_waitcnt vmcnt(4)" ::: "memory");
    else if ((s + 1) < NT) asm volatile("s_waitcnt vmcnt(0)" ::: "memory");
    __builtin_amdgcn_s_barrier();
    __builtin_amdgcn_sched_barrier(0);
  }

#pragma unroll
  for (int mi = 0; mi < 8; ++mi) {
    const int m = m0 + wm * 128 + mi * 16 + hi * 4;
#pragma unroll
    for (int j = 0; j < 2; ++j) {
      const int n = n0 + wn * 32 + j * 16 + r16;
#pragma unroll
      for (int q = 0; q < 4; ++q) {
        float u = accU[mi][j][q];
        float g = accG[mi][j][q];
        float sg = g / (1.0f + __expf(-g));
        Cp[(size_t)(m + q) * N + n] = (bf16)(sg * u);
      }
    }
  }
}

// ---------------- GEMM B: BMxBN ring (generalized; LA/LB staging passes) ----------------

template <int BM, int BN, int WMW, int WNW, int EP>
__global__ __launch_bounds__(WMW * WNW * 64, 2) void gemmk(
    const bf16* __restrict__ A, const bf16* __restrict__ Bt, void* __restrict__ Cp,
    const float* __restrict__ bias, const bf16* __restrict__ aux,
    int M, int N, int K) {
  constexpr int BK = 32;
  constexpr int MF = BM / (WMW * 16);
  constexpr int NF = BN / (WNW * 16);
  constexpr int LA = BM / 64;
  constexpr int LB = BN / 64;
  constexpr int VM_MAIN = 2 * LA + LB;
  constexpr int VM_TAIL = LA + LB;
  __shared__ bf16 sA[4][BM * BK];
  __shared__ bf16 sB[4][BN * BK];

  const int tid = threadIdx.x;
  const int lane = tid & 63;
  const int r16 = lane & 15, hi = lane >> 4;
  const int wave = tid >> 6;
  const int wm = wave / WNW, wn = wave % WNW;

  const int nwg = gridDim.x;
  const int orig = blockIdx.x;
  const int qq = nwg >> 3, rr = nwg & 7;
  const int xcd = orig & 7, cidx = orig >> 3;
  const int wg = (xcd < rr ? xcd * (qq + 1) : rr * (qq + 1) + (xcd - rr) * qq) + cidx;
  const int gM = M / BM;
  const int m0 = (wg % gM) * BM;
  const int n0 = (wg / gM) * BN;

  const int srow = tid >> 2;
  const int ccol = tid & 3;
  const int skey = (srow >> 1) & 3;
  const int gcol = ((ccol ^ skey)) * 8;
  const bf16* aS = A + (size_t)(m0 + srow) * K + gcol;
  const bf16* bS = Bt + (size_t)(n0 + srow) * K + gcol;
  const int dst0 = srow * BK + ccol * 8;

  const int rkey = (r16 >> 1) & 3;
  const int rchunk = (hi ^ rkey) * 8;

  f32x4 acc[MF][NF] = {};
  const int NT = K / BK;

#pragma unroll
  for (int t0_ = 0; t0_ < 2; ++t0_) {
#pragma unroll
    for (int p = 0; p < LA; ++p)
      gld16(aS + t0_ * BK + (size_t)p * 64 * K, &sA[t0_][dst0 + p * 64 * BK]);
#pragma unroll
    for (int p = 0; p < LB; ++p)
      gld16(bS + t0_ * BK + (size_t)p * 64 * K, &sB[t0_][dst0 + p * 64 * BK]);
  }

  for (int t = 0; t < NT; ++t) {
    const int cb = t & 3;
    const int pb = (t + 2) & 3;
    const bool pre = (t + 2) < NT;
    if (pre) {
#pragma unroll
      for (int p = 0; p < LA; ++p)
        gld16(aS + (size_t)(t + 2) * BK + (size_t)p * 64 * K, &sA[pb][dst0 + p * 64 * BK]);
    }
    if (pre)             asm volatile("s_waitcnt vmcnt(%0)" :: "i"(VM_MAIN) : "memory");
    else if (t + 1 < NT) asm volatile("s_waitcnt vmcnt(%0)" :: "i"(VM_TAIL) : "memory");
    else                 asm volatile("s_waitcnt vmcnt(0)" ::: "memory");
    __builtin_amdgcn_s_barrier();
    __builtin_amdgcn_sched_barrier(0);

    bf16x8 bf_[NF];
#pragma unroll
    for (int j = 0; j < NF; ++j)
      bf_[j] = *(const bf16x8*)&sB[cb][(wn * (NF * 16) + j * 16 + r16) * BK + rchunk];
    if (pre) {
#pragma unroll
      for (int p = 0; p < LB; ++p)
        gld16(bS + (size_t)(t + 2) * BK + (size_t)p * 64 * K, &sB[pb][dst0 + p * 64 * BK]);
    }
    bf16x8 af[MF];
#pragma unroll
    for (int i = 0; i < MF; ++i)
      af[i] = *(const bf16x8*)&sA[cb][(wm * (MF * 16) + i * 16 + r16) * BK + rchunk];
    __builtin_amdgcn_s_setprio(1);
#pragma unroll
    for (int i = 0; i < MF; ++i)
#pragma unroll
      for (int j = 0; j < NF; ++j)
        acc[i][j] = __builtin_amdgcn_mfma_f32_16x16x32_bf16(af[i], bf_[j], acc[i][j], 0, 0, 0);
    __builtin_amdgcn_s_setprio(0);
  }

#pragma unroll
  for (int i = 0; i < MF; ++i) {
    const int m = m0 + wm * (MF * 16) + i * 16 + hi * 4;
#pragma unroll
    for (int j = 0; j < NF; ++j) {
      const int n = n0 + wn * (NF * 16) + j * 16 + r16;
#pragma unroll
      for (int q = 0; q < 4; ++q) {
        size_t idx = (size_t)(m + q) * N + n;
        float v = acc[i][j][q];
        if constexpr (EP == EP_F32) {
          ((float*)Cp)[idx] = v;
        } else if constexpr (EP == EP_F32_BIAS) {
          ((float*)Cp)[idx] = v + bias[n];
        } else if constexpr (EP == EP_BF16) {
          ((bf16*)Cp)[idx] = (bf16)v;
        } else if constexpr (EP == EP_BF16_BIAS) {
          ((bf16*)Cp)[idx] = (bf16)(v + bias[n]);
        } else {
          float sg = v / (1.0f + __expf(-v));
          ((bf16*)Cp)[idx] = (bf16)(sg * (float)aux[idx]);
        }
      }
    }
  }
}

// ---------------- flash attention: swapped QK^T, QBLK=128 (2 Q-frags/wave) ----------------

__global__ __launch_bounds__(256, 2) void attn_flash(
    const bf16* __restrict__ Qp, const bf16* __restrict__ Kp, int ldk,
    const bf16* __restrict__ Vt, bf16* __restrict__ Op) {
  __shared__ bf16 Ks[2][128 * 32];
  __shared__ bf16 Vs[4][64 * 32];
  __shared__ bf16 Ps[4][2][16 * 144];
  const int tid = threadIdx.x, lane = tid & 63, wave = tid >> 6;
  const int h = blockIdx.y, b = blockIdx.z;
  const int r16 = lane & 15, hi = lane >> 4;
  const int qbase = blockIdx.x * 128 + wave * 32;

  const float QS = 0.1803368801f;          // 0.125 * log2(e)
  bf16x8 qa[2][2];
#pragma unroll
  for (int f = 0; f < 2; ++f) {
    const bf16* qp = Qp + (size_t)(b * TT + qbase + f * 16 + r16) * ldk + h * DH + hi * 8;
    bf16x8 q0 = *(const bf16x8*)qp;
    bf16x8 q1 = *(const bf16x8*)(qp + 32);
#pragma unroll
    for (int e = 0; e < 8; ++e) {
      qa[f][0][e] = (bf16)((float)q0[e] * QS);
      qa[f][1][e] = (bf16)((float)q1[e] * QS);
    }
  }
  const bf16* kBase = Kp + (size_t)(b * TT) * ldk + h * DH;
  const bf16* vBase = Vt + (size_t)(b * NH + h) * DH * TT;

  const int srow = tid >> 2, ccol = tid & 3;
  const int skey = (srow >> 1) & 3;
  const int scolS = (ccol ^ skey) * 8;
  const int dstc = ccol * 8;
  const int rkey = (r16 >> 1) & 3;
  const int rchunk = (hi ^ rkey) * 8;

  float m_run[2] = {-1e30f, -1e30f};
  float l_run[2] = {0.f, 0.f};
  f32x4 oacc[2][4] = {};

  for (int kt = 0; kt < TT; kt += 128) {
#pragma unroll
    for (int half = 0; half < 2; ++half) {
      gld16(kBase + (size_t)(kt + srow) * ldk + half * 32 + scolS, &Ks[half][srow * 32 + dstc]);
      gld16(kBase + (size_t)(kt + 64 + srow) * ldk + half * 32 + scolS, &Ks[half][(64 + srow) * 32 + dstc]);
    }
#pragma unroll
    for (int ks = 0; ks < 4; ++ks)
      gld16(vBase + (size_t)srow * TT + kt + ks * 32 + scolS, &Vs[ks][srow * 32 + dstc]);
    __syncthreads();

#pragma unroll
    for (int f = 0; f < 2; ++f) {
      f32x4 s[8];
      __builtin_amdgcn_s_setprio(1);
#pragma unroll
      for (int kg = 0; kg < 8; ++kg) {
        f32x4 z = {};
        bf16x8 kb0 = *(const bf16x8*)&Ks[0][(kg * 16 + r16) * 32 + rchunk];
        bf16x8 kb1 = *(const bf16x8*)&Ks[1][(kg * 16 + r16) * 32 + rchunk];
        z = __builtin_amdgcn_mfma_f32_16x16x32_bf16(kb0, qa[f][0], z, 0, 0, 0);
        z = __builtin_amdgcn_mfma_f32_16x16x32_bf16(kb1, qa[f][1], z, 0, 0, 0);
        s[kg] = z;
      }
      __builtin_amdgcn_s_setprio(0);

      float pm = s[0][0];
#pragma unroll
      for (int kg = 0; kg < 8; ++kg)
#pragma unroll
        for (int i = 0; i < 4; ++i) pm = fmaxf(pm, s[kg][i]);
      pm = fmaxf(pm, __shfl_xor(pm, 16));
      pm = fmaxf(pm, __shfl_xor(pm, 32));

      if (!__all(pm - m_run[f] <= 11.5411f)) {
        float mnew = fmaxf(m_run[f], pm);
        float fr = exp2f(m_run[f] - mnew);
        m_run[f] = mnew;
        l_run[f] *= fr;
#pragma unroll
        for (int i = 0; i < 4; ++i) {
          float fi = __shfl(fr, hi * 4 + i);
#pragma unroll
          for (int n = 0; n < 4; ++n) oacc[f][n][i] *= fi;
        }
      }

      float lsum = 0.f;
#pragma unroll
      for (int kg = 0; kg < 8; ++kg) {
        float p0 = exp2f(s[kg][0] - m_run[f]);
        float p1 = exp2f(s[kg][1] - m_run[f]);
        float p2 = exp2f(s[kg][2] - m_run[f]);
        float p3 = exp2f(s[kg][3] - m_run[f]);
        lsum += (p0 + p1) + (p2 + p3);
        bf16x4 pk = {(bf16)p0, (bf16)p1, (bf16)p2, (bf16)p3};
        *(bf16x4*)&Ps[wave][f][r16 * 144 + kg * 16 + hi * 4] = pk;
      }
      l_run[f] += lsum;

      __builtin_amdgcn_s_setprio(1);
#pragma unroll
      for (int ks = 0; ks < 4; ++ks) {
        bf16x8 pa = *(const bf16x8*)&Ps[wave][f][r16 * 144 + ks * 32 + hi * 8];
#pragma unroll
        for (int n = 0; n < 4; ++n) {
          bf16x8 vb = *(const bf16x8*)&Vs[ks][(n * 16 + r16) * 32 + rchunk];
          oacc[f][n] = __builtin_amdgcn_mfma_f32_16x16x32_bf16(pa, vb, oacc[f][n], 0, 0, 0);
        }
      }
      __builtin_amdgcn_s_setprio(0);
    }
    __syncthreads();
  }

#pragma unroll
  for (int f = 0; f < 2; ++f) {
    float lq = l_run[f];
    lq += __shfl_xor(lq, 16);
    lq += __shfl_xor(lq, 32);
    float invq = 1.0f / lq;
#pragma unroll
    for (int i = 0; i < 4; ++i) {
      float inv_i = __shfl(invq, hi * 4 + i);
      int trow = qbase + f * 16 + hi * 4 + i;
      size_t base = ((size_t)b * TT + trow) * DIM + h * DH;
#pragma unroll
      for (int n = 0; n < 4; ++n)
        Op[base + n * 16 + r16] = (bf16)(oacc[f][n][i] * inv_i);
    }
  }
}

// ---------------- residual + rmsnorm (y bf16; residual accum fp32 via xf) ----------------

__global__ __launch_bounds__(256) void resid_rms(
    const float* __restrict__ xin, const bf16* __restrict__ y, const float* __restrict__ wgt,
    float* __restrict__ xf_out, bf16* __restrict__ xb_out) {
  __shared__ float red[4];
  const int r = blockIdx.x, tid = threadIdx.x;
  const size_t base = (size_t)r * DIM + tid * 4;
  float4 v = *(const float4*)(xin + base);
  bf16x4 ub = *(const bf16x4*)(y + base);
  v.x += (float)ub[0]; v.y += (float)ub[1]; v.z += (float)ub[2]; v.w += (float)ub[3];
  float ss = v.x * v.x + v.y * v.y + v.z * v.z + v.w * v.w;
#pragma unroll
  for (int d = 1; d < 64; d <<= 1) ss += __shfl_xor(ss, d);
  if ((tid & 63) == 0) red[tid >> 6] = ss;
  __syncthreads();
  ss = red[0] + red[1] + red[2] + red[3];
  float sc = rsqrtf(ss * (1.0f / DIM) + 1e-8f);
  const float4 wv = *(const float4*)(wgt + tid * 4);
  float o0 = v.x * sc * wv.x, o1 = v.y * sc * wv.y, o2 = v.z * sc * wv.z, o3 = v.w * sc * wv.w;
  if (xf_out) {
    float4 ov = {o0, o1, o2, o3};
    *(float4*)(xf_out + base) = ov;
  }
  bf16x4 ob = {(bf16)o0, (bf16)o1, (bf16)o2, (bf16)o3};
  *(bf16x4*)(xb_out + base) = ob;
}

// ---------------- slot softmax rows (bf16 scores in; scale D^-0.5 = 1/32) ----------------

__global__ __launch_bounds__(256) void softmax_rows(const bf16* __restrict__ Sc, bf16* __restrict__ P) {
  __shared__ float red[4];
  const int r = blockIdx.x, tid = threadIdx.x;
  const bf16* row = Sc + (size_t)r * NSLOT;
  float v[16];
#pragma unroll
  for (int i = 0; i < 4; ++i) {
    bf16x4 b4 = *(const bf16x4*)(row + tid * 4 + i * 1024);
    v[i * 4 + 0] = (float)b4[0]; v[i * 4 + 1] = (float)b4[1];
    v[i * 4 + 2] = (float)b4[2]; v[i * 4 + 3] = (float)b4[3];
  }
  float mx = -1e30f;
#pragma unroll
  for (int k = 0; k < 16; ++k) mx = fmaxf(mx, v[k]);
#pragma unroll
  for (int d = 1; d < 64; d <<= 1) mx = fmaxf(mx, __shfl_xor(mx, d));
  if ((tid & 63) == 0) red[tid >> 6] = mx;
  __syncthreads();
  mx = fmaxf(fmaxf(red[0], red[1]), fmaxf(red[2], red[3]));
  __syncthreads();
  float e[16];
  float sum = 0.f;
#pragma unroll
  for (int k = 0; k < 16; ++k) {
    e[k] = __expf((v[k] - mx) * 0.03125f);
    sum += e[k];
  }
#pragma unroll
  for (int d = 1; d < 64; d <<= 1) sum += __shfl_xor(sum, d);
  if ((tid & 63) == 0) red[tid >> 6] = sum;
  __syncthreads();
  sum = red[0] + red[1] + red[2] + red[3];
  float inv = 1.0f / sum;
#pragma unroll
  for (int i = 0; i < 4; ++i) {
    bf16x4 ob = {(bf16)(e[i * 4 + 0] * inv), (bf16)(e[i * 4 + 1] * inv),
                 (bf16)(e[i * 4 + 2] * inv), (bf16)(e[i * 4 + 3] * inv)};
    *(bf16x4*)(P + (size_t)r * NSLOT + tid * 4 + i * 1024) = ob;
  }
}

// ---------------- host orchestration ----------------

extern "C" void kernel_launch(void* const* d_in, const int* in_sizes, int n_in,
                              void* d_out, int out_size, void* d_ws, size_t ws_size,
                              hipStream_t stream) {
  (void)in_sizes; (void)n_in; (void)out_size;
  const int* ids = (const int*)d_in[0];
  const float* emb = (const float*)d_in[1];
  const float* Wq = (const float*)d_in[2];
  const float* Wk = (const float*)d_in[3];
  const float* Wv = (const float*)d_in[4];
  const float* Wo = (const float*)d_in[5];
  const float* bo = (const float*)d_in[6];
  const float* n1 = (const float*)d_in[7];
  const float* Wg = (const float*)d_in[8];
  const float* Wu = (const float*)d_in[9];
  const float* Wd = (const float*)d_in[10];
  const float* n2 = (const float*)d_in[11];
  const float* memp = (const float*)d_in[12];
  const float* Wsp = (const float*)d_in[13];
  const float* bsp = (const float*)d_in[14];
  const float* Wrp = (const float*)d_in[15];
  const float* brp = (const float*)d_in[16];
  const float* nout = (const float*)d_in[17];

  char* w = (char*)d_ws;
  auto alloc = [&](size_t bytes) -> void* {
    void* p = (void*)w;
    w += (bytes + 255) & ~(size_t)255;
    return p;
  };

  const size_t dd = (size_t)DIM * DIM;
  const size_t dff = (size_t)DIM * FFD;

  bf16* tok_b = (bf16*)alloc((size_t)NV * DIM * 2);
  bf16* mem_b = (bf16*)alloc((size_t)NSLOT * DIM * 2);
  bf16* memT  = (bf16*)alloc((size_t)NSLOT * DIM * 2);
  bf16* WspT  = (bf16*)alloc(dd * 2);
  bf16* WrpT  = (bf16*)alloc(dd * 2);
  float* xf   = (float*)alloc((size_t)BT * DIM * 4);
  bf16* xb    = (bf16*)alloc((size_t)BT * DIM * 2);
  bf16* yb    = (bf16*)alloc((size_t)BT * DIM * 2);   // GEMM outputs, bf16
  bf16* W3T   = (bf16*)alloc(3 * dd * 2);   // [WqT | WkT | WvT] rows
  bf16* WoT   = (bf16*)alloc(dd * 2);
  bf16* WgT   = (bf16*)alloc(dff * 2);
  bf16* WuT   = (bf16*)alloc(dff * 2);
  bf16* WdT   = (bf16*)alloc(dff * 2);
  bf16* qkv   = (bf16*)alloc((size_t)BT * 3 * DIM * 2);
  bf16* vT_   = (bf16*)alloc((size_t)BT * DIM * 2);
  bf16* ot_   = (bf16*)alloc((size_t)BT * DIM * 2);
  bf16* qb    = (bf16*)alloc((size_t)BT * DIM * 2);
  bf16* rb    = (bf16*)alloc((size_t)BT * DIM * 2);
  bf16* hb    = (bf16*)alloc((size_t)BT * DIM * 2);

  size_t used = (size_t)(w - (char*)d_ws);
  size_t region_bytes = (size_t)BT * NSLOT * 2 * 2;  // bf16 scores + bf16 attn
  char* region;
  if (used + region_bytes <= ws_size) region = (char*)alloc(region_bytes);
  else region = (char*)d_out;
  bf16* Hb = (bf16*)region;
  bf16* scoresB = (bf16*)region;
  bf16* attnb = (bf16*)(region + (size_t)BT * NSLOT * 2);

  dim3 blkT(8, 32);
  dim3 blkV(32, 8);

  cvt_bf16<<<NV * DIM / 1024, 256, 0, stream>>>(emb, tok_b, (long)NV * DIM);
  cvt_bf16<<<NSLOT * DIM / 1024, 256, 0, stream>>>(memp, mem_b, (long)NSLOT * DIM);
  {
    TBatch tb{};
    tb.src[0] = memp; tb.dst[0] = memT; tb.R[0] = NSLOT; tb.C[0] = DIM; tb.base[0] = 0;
    tb.src[1] = Wsp;  tb.dst[1] = WspT; tb.R[1] = DIM;   tb.C[1] = DIM; tb.base[1] = 4096;
    tb.src[2] = Wrp;  tb.dst[2] = WrpT; tb.R[2] = DIM;   tb.C[2] = DIM; tb.base[2] = 5120;
    for (int i = 3; i < 7; ++i) { tb.base[i] = 0x7fffffff; tb.src[i] = memp; tb.dst[i] = memT; tb.R[i] = 32; tb.C[i] = 32; }
    transpose_cvt_batch<<<6144, blkT, 0, stream>>>(tb);
  }
  embed_rope<<<BT, 256, 0, stream>>>(ids, emb, xf, xb);

  for (int l = 0; l < NL; ++l) {
    {
      TBatch tb{};
      tb.src[0] = Wq + l * dd;  tb.dst[0] = W3T;          tb.R[0] = DIM; tb.C[0] = DIM;  tb.base[0] = 0;
      tb.src[1] = Wk + l * dd;  tb.dst[1] = W3T + dd;     tb.R[1] = DIM; tb.C[1] = DIM;  tb.base[1] = 1024;
      tb.src[2] = Wv + l * dd;  tb.dst[2] = W3T + 2 * dd; tb.R[2] = DIM; tb.C[2] = DIM;  tb.base[2] = 2048;
      tb.src[3] = Wo + l * dd;  tb.dst[3] = WoT;          tb.R[3] = DIM; tb.C[3] = DIM;  tb.base[3] = 3072;
      tb.src[4] = Wg + l * dff; tb.dst[4] = WgT;          tb.R[4] = DIM; tb.C[4] = FFD;  tb.base[4] = 4096;
      tb.src[5] = Wu + l * dff; tb.dst[5] = WuT;          tb.R[5] = DIM; tb.C[5] = FFD;  tb.base[5] = 8192;
      tb.src[6] = Wd + l * dff; tb.dst[6] = WdT;          tb.R[6] = FFD; tb.C[6] = DIM;  tb.base[6] = 12288;
      transpose_cvt_batch<<<16384, blkT, 0, stream>>>(tb);
    }

    gemm8<EP_BF16><<<dim3(16 * 12), 512, 0, stream>>>(
        xb, W3T, qkv, nullptr, nullptr, BT, 3 * DIM, DIM);
    transpose_v<<<dim3(TT / 32, DH / 32, BB * NH), blkV, 0, stream>>>(qkv + 2 * DIM, 3 * DIM, vT_);
    attn_flash<<<dim3(TT / 128, NH, BB), 256, 0, stream>>>(qkv, qkv + DIM, 3 * DIM, vT_, ot_);
    gemmk<128, 64, 2, 2, EP_BF16_BIAS><<<dim3(32 * 16), 256, 0, stream>>>(
        ot_, WoT, yb, bo + l * DIM, nullptr, BT, DIM, DIM);
    resid_rms<<<BT, 256, 0, stream>>>(xf, yb, n1 + l * DIM, xf, xb);
    gemm8ff<<<dim3(16 * 32), 512, 0, stream>>>(
        xb, WuT, WgT, Hb, BT, FFD, DIM);
    gemmk<128, 64, 2, 2, EP_BF16><<<dim3(32 * 16), 256, 0, stream>>>(
        Hb, WdT, yb, nullptr, nullptr, BT, DIM, FFD);
    resid_rms<<<BT, 256, 0, stream>>>(xf, yb, n2 + l * DIM, xf, xb);
  }

  gemmk<128, 64, 2, 2, EP_BF16_BIAS><<<dim3(32 * 16), 256, 0, stream>>>(
      xb, WspT, qb, bsp, nullptr, BT, DIM, DIM);
  gemm8<EP_BF16><<<dim3(16 * 16), 512, 0, stream>>>(
      qb, mem_b, scoresB, nullptr, nullptr, BT, NSLOT, DIM);
  softmax_rows<<<BT, 256, 0, stream>>>(scoresB, attnb);
  gemmk<128, 64, 2, 2, EP_BF16><<<dim3(32 * 16), 256, 0, stream>>>(
      attnb, memT, rb, nullptr, nullptr, BT, DIM, NSLOT);
  gemmk<128, 64, 2, 2, EP_BF16_BIAS><<<dim3(32 * 16), 256, 0, stream>>>(
      rb, WrpT, yb, brp, nullptr, BT, DIM, DIM);
  resid_rms<<<BT, 256, 0, stream>>>(xf, yb, nout, nullptr, hb);
  gemm8<EP_F32><<<dim3(16 * 125), 512, 0, stream>>>(
      hb, tok_b, (float*)d_out, nullptr, nullptr, BT, NV, DIM);
}